// Round 2
// baseline (2116.060 us; speedup 1.0000x reference)
//
#include <hip/hip_runtime.h>
#include <stdint.h>

#define N_NODES  100000
#define N_EDGES  250000
#define N_GRAPHS 2000
#define F_IN     75
#define DIM      32
#define H1       128

#define MSG_BLOCKS 1954          // ceil(250000/128) edge-blocks of 128
#define KT_STEPS   129           // 128 kt for W2 (c=4096) + 1 kt for b2 fold-in
#define W2F_HALFS  (KT_STEPS * 1024)

typedef _Float16 v8h __attribute__((ext_vector_type(8)));
typedef float    v4f __attribute__((ext_vector_type(4)));

// order-preserving float->uint encoding for atomicMax
__device__ __forceinline__ unsigned fenc(float f) {
    unsigned u = __float_as_uint(f);
    return (u & 0x80000000u) ? ~u : (u | 0x80000000u);
}
__device__ __forceinline__ float fdec(unsigned e) {
    unsigned u = (e & 0x80000000u) ? (e & 0x7FFFFFFFu) : ~e;
    return __uint_as_float(u);
}

// -------- lin0: h = relu(nf @ W.T + b), [N,75]->[N,32]; h lives in d_out --------
__global__ __launch_bounds__(256) void lin0_kernel(
    const float* __restrict__ nf, const float* __restrict__ w,
    const float* __restrict__ b, float* __restrict__ h) {
    __shared__ float wl[DIM * F_IN];
    __shared__ float bl[DIM];
    int t = threadIdx.x;
    for (int i = t; i < DIM * F_IN; i += 256) wl[i] = w[i];
    if (t < DIM) bl[t] = b[t];
    __syncthreads();
    int n = blockIdx.x * 8 + (t >> 5);
    int o = t & 31;
    if (n >= N_NODES) return;
    const float* row = nf + n * F_IN;
    float acc = bl[o];
    #pragma unroll
    for (int i = 0; i < F_IN; ++i) acc += row[i] * wl[o * F_IN + i];
    h[n * DIM + o] = fmaxf(acc, 0.f);
}

// -------- build W2t fragment-major fp16 table (+ b2 as kt=128) --------
// id = kt*1024 + ng*512 + lane*8 + j ; lane=(q*16+lr); c = kt*32+q*8+j; o = ng*16+lr
// c < 4096: val = W2[(c>>7)*32 + o, c&127];  c >= 4096: val = b2[(c-4096)*32 + o]
__global__ __launch_bounds__(256) void prep_w2f_kernel(
    const float* __restrict__ w2, const float* __restrict__ b2,
    _Float16* __restrict__ w2f) {
    int id = blockIdx.x * 256 + threadIdx.x;
    if (id >= W2F_HALFS) return;
    int j    = id & 7;
    int lane = (id >> 3) & 63;
    int ng   = (id >> 9) & 1;
    int kt   = id >> 10;
    int lr = lane & 15, q = lane >> 4;
    int c = kt * 32 + q * 8 + j;
    int o = ng * 16 + lr;
    float val;
    if (c < 4096) val = w2[((c >> 7) * 32 + o) * H1 + (c & 127)];
    else          val = b2[(c - 4096) * 32 + o];
    w2f[id] = (_Float16)val;
}

// -------- edge hidden hw = relu(ef @ W1.T + b1), fp16, FRAG-MAJOR layout --------
// tile = local_e>>4; addr = tile*2048 + (k>>3)*128 + (local_e&15)*8 + (k&7)
__global__ __launch_bounds__(256) void hw_kernel(
    const float* __restrict__ ef, const float* __restrict__ w1,
    const float* __restrict__ b1, _Float16* __restrict__ hwf,
    int e_off) {
    __shared__ float wl[H1 * 11];
    __shared__ float bl[H1];
    int t = threadIdx.x;
    for (int i = t; i < H1 * 11; i += 256) wl[i] = w1[i];
    if (t < H1) bl[t] = b1[t];
    __syncthreads();
    int le = blockIdx.x * 2 + (t >> 7);          // local edge index in chunk
    int k  = t & 127;
    int e  = e_off + le;                          // global edge
    float acc = 0.f;
    if (e < N_EDGES) {
        const float* row = ef + (size_t)e * 11;
        acc = bl[k];
        #pragma unroll
        for (int i = 0; i < 11; ++i) acc += row[i] * wl[k * 11 + i];
        acc = fmaxf(acc, 0.f);
    }
    size_t addr = (size_t)(le >> 4) * 2048 + (k >> 3) * 128 + (le & 15) * 8 + (k & 7);
    hwf[addr] = (_Float16)acc;
}

// -------- in-degree counts --------
__global__ __launch_bounds__(256) void cnt_kernel(
    const int* __restrict__ dst, float* __restrict__ cnt) {
    int e = blockIdx.x * 256 + threadIdx.x;
    if (e < N_EDGES) atomicAdd(&cnt[dst[e]], 1.0f);
}

// -------- fused message GEMM: msg = G @ W2t, G synthesized in regs --------
// block = 128 threads (2 waves), 128 edges; wave: 64 edges (4 m-tiles) x 32 o (2 n-tiles)
__global__ __launch_bounds__(128) void msg_kernel(
    const _Float16* __restrict__ hwf, const _Float16* __restrict__ w2f,
    const float* __restrict__ x, const int* __restrict__ src,
    const int* __restrict__ dst, float* __restrict__ sbuf, int e_off) {
    __shared__ _Float16 xs[32 * 128];   // xs[i][e_loc], 8 KB

    int t = threadIdx.x;
    // stage x[src] tile (fp32 -> fp16), one edge per thread
    {
        int e = e_off + blockIdx.x * 128 + t;
        int ec = e < N_EDGES ? e : N_EDGES - 1;
        int sv = src[ec];
        const float4* xr = (const float4*)(x + (size_t)sv * DIM);
        #pragma unroll
        for (int u = 0; u < 8; ++u) {
            float4 v = xr[u];
            xs[(u * 4 + 0) * 128 + t] = (_Float16)v.x;
            xs[(u * 4 + 1) * 128 + t] = (_Float16)v.y;
            xs[(u * 4 + 2) * 128 + t] = (_Float16)v.z;
            xs[(u * 4 + 3) * 128 + t] = (_Float16)v.w;
        }
    }

    int w = t >> 6, lane = t & 63;
    int lr = lane & 15, q = lane >> 4;
    int wbase = w * 64;

    // preload all hw fragments for this wave's 64 edges: 4 m-tiles x 4 k-chunks
    v8h hwr[4][4];
    int T0 = blockIdx.x * 8 + w * 4;
    const v8h* hv = (const v8h*)hwf;
    #pragma unroll
    for (int mt = 0; mt < 4; ++mt)
        #pragma unroll
        for (int kc = 0; kc < 4; ++kc)
            hwr[mt][kc] = hv[(size_t)(T0 + mt) * 256 + (kc * 4 + q) * 16 + lr];

    __syncthreads();

    v4f acc[4][2];
    #pragma unroll
    for (int mt = 0; mt < 4; ++mt)
        #pragma unroll
        for (int ng = 0; ng < 2; ++ng) { v4f z = {0.f,0.f,0.f,0.f}; acc[mt][ng] = z; }

    const v8h* bv = (const v8h*)w2f;
    v8h b0 = bv[0 * 128 + 0 * 64 + lane];
    v8h b1 = bv[0 * 128 + 1 * 64 + lane];
    v8h xsp[4];

    for (int kt = 0; kt < KT_STEPS; ++kt) {
        v8h nb0, nb1;
        if (kt + 1 < KT_STEPS) {
            nb0 = bv[(kt + 1) * 128 + 0 * 64 + lane];
            nb1 = bv[(kt + 1) * 128 + 1 * 64 + lane];
        }
        v8h a[4];
        if (kt < 128) {
            if ((kt & 3) == 0) {
                int i = kt >> 2;
                #pragma unroll
                for (int mt = 0; mt < 4; ++mt) {
                    _Float16 xh = xs[i * 128 + wbase + mt * 16 + lr];
                    #pragma unroll
                    for (int j = 0; j < 8; ++j) xsp[mt][j] = xh;
                }
            }
            int kc = kt & 3;
            #pragma unroll
            for (int mt = 0; mt < 4; ++mt) a[mt] = xsp[mt] * hwr[mt][kc];
        } else {
            // bias fold-in step: A = x[src, q*8+j] directly
            #pragma unroll
            for (int mt = 0; mt < 4; ++mt)
                #pragma unroll
                for (int j = 0; j < 8; ++j)
                    a[mt][j] = xs[(q * 8 + j) * 128 + wbase + mt * 16 + lr];
        }
        #pragma unroll
        for (int mt = 0; mt < 4; ++mt) {
            acc[mt][0] = __builtin_amdgcn_mfma_f32_16x16x32_f16(a[mt], b0, acc[mt][0], 0, 0, 0);
            acc[mt][1] = __builtin_amdgcn_mfma_f32_16x16x32_f16(a[mt], b1, acc[mt][1], 0, 0, 0);
        }
        b0 = nb0; b1 = nb1;
    }

    // epilogue: D[m = q*4+r][n = lr] ; scatter-add to sbuf[dst]
    int E0 = e_off + blockIdx.x * 128 + wbase;
    #pragma unroll
    for (int mt = 0; mt < 4; ++mt) {
        #pragma unroll
        for (int r = 0; r < 4; ++r) {
            int e = E0 + mt * 16 + q * 4 + r;
            if (e < N_EDGES) {
                int dv = dst[e];
                float* sp = sbuf + (size_t)dv * DIM;
                atomicAdd(sp + lr,      acc[mt][0][r]);
                atomicAdd(sp + 16 + lr, acc[mt][1][r]);
            }
        }
    }
}

// -------- fused scatter-mean finalize + conv_bias + relu + GRU cell --------
__global__ __launch_bounds__(256) void gru_kernel(
    const float* __restrict__ s, const float* __restrict__ cnt,
    const float* __restrict__ cb,
    const float* __restrict__ wih, const float* __restrict__ whh,
    const float* __restrict__ bih, const float* __restrict__ bhh,
    float* __restrict__ h) {
    __shared__ float wi[96 * 33], wh[96 * 33];
    __shared__ float bi[96], bh[96], cbl[DIM];
    __shared__ float ml[8][DIM], hl[8][DIM];
    int t = threadIdx.x;
    for (int i = t; i < 96 * DIM; i += 256) {
        int r = i >> 5, c = i & 31;
        wi[r * 33 + c] = wih[i];
        wh[r * 33 + c] = whh[i];
    }
    if (t < 96) { bi[t] = bih[t]; bh[t] = bhh[t]; }
    if (t < DIM) cbl[t] = cb[t];
    __syncthreads();
    int nl = t >> 5, o = t & 31;
    int n = blockIdx.x * 8 + nl;
    if (n < N_NODES) {
        float c = cnt[n];
        c = c > 1.f ? c : 1.f;
        float m = s[n * DIM + o] / c + cbl[o];
        ml[nl][o] = fmaxf(m, 0.f);
        hl[nl][o] = h[n * DIM + o];
    }
    __syncthreads();
    if (n >= N_NODES) return;
    float gir = bi[o],      giz = bi[32 + o], gin = bi[64 + o];
    float ghr = bh[o],      ghz = bh[32 + o], ghn = bh[64 + o];
    #pragma unroll
    for (int i = 0; i < DIM; ++i) {
        float mv = ml[nl][i], hv = hl[nl][i];
        gir += mv * wi[o * 33 + i];
        giz += mv * wi[(32 + o) * 33 + i];
        gin += mv * wi[(64 + o) * 33 + i];
        ghr += hv * wh[o * 33 + i];
        ghz += hv * wh[(32 + o) * 33 + i];
        ghn += hv * wh[(64 + o) * 33 + i];
    }
    float r  = 1.f / (1.f + expf(-(gir + ghr)));
    float z  = 1.f / (1.f + expf(-(giz + ghz)));
    float nn = tanhf(gin + r * ghn);
    h[n * DIM + o] = (1.f - z) * nn + z * hl[nl][o];
}

// -------- Set2Set step 1: LSTM cell; re-init softmax accumulators --------
__global__ __launch_bounds__(256) void s2s_lstm_kernel(
    const float* __restrict__ qstar,
    const float* __restrict__ wih, const float* __restrict__ whh,
    const float* __restrict__ bih, const float* __restrict__ bhh,
    float* __restrict__ h, float* __restrict__ c,
    float* __restrict__ rnum, float* __restrict__ denom,
    unsigned* __restrict__ emax) {
    __shared__ float wi[128 * 65];
    __shared__ float wh[128 * 33];
    __shared__ float bl[128], bhl[128];
    __shared__ float ql[8][64], hl[8][32], cl[8][32];
    int t = threadIdx.x;
    for (int i = t; i < 128 * 64; i += 256) { int r = i >> 6, cc = i & 63; wi[r * 65 + cc] = wih[i]; }
    for (int i = t; i < 128 * 32; i += 256) { int r = i >> 5, cc = i & 31; wh[r * 33 + cc] = whh[i]; }
    if (t < 128) { bl[t] = bih[t]; bhl[t] = bhh[t]; }
    int gl = t >> 5, o = t & 31;
    int b = blockIdx.x * 8 + gl;
    if (b < N_GRAPHS) {
        ql[gl][o]      = qstar[b * 64 + o];
        ql[gl][32 + o] = qstar[b * 64 + 32 + o];
        hl[gl][o]      = h[b * DIM + o];
        cl[gl][o]      = c[b * DIM + o];
    }
    __syncthreads();
    if (b >= N_GRAPHS) return;
    float gi = bl[o]      + bhl[o];
    float gf = bl[32 + o] + bhl[32 + o];
    float gg = bl[64 + o] + bhl[64 + o];
    float go = bl[96 + o] + bhl[96 + o];
    #pragma unroll
    for (int i = 0; i < 64; ++i) {
        float qv = ql[gl][i];
        gi += qv * wi[o * 65 + i];
        gf += qv * wi[(32 + o) * 65 + i];
        gg += qv * wi[(64 + o) * 65 + i];
        go += qv * wi[(96 + o) * 65 + i];
    }
    #pragma unroll
    for (int i = 0; i < 32; ++i) {
        float hv = hl[gl][i];
        gi += hv * wh[o * 33 + i];
        gf += hv * wh[(32 + o) * 33 + i];
        gg += hv * wh[(64 + o) * 33 + i];
        go += hv * wh[(96 + o) * 33 + i];
    }
    float si = 1.f / (1.f + expf(-gi));
    float sf = 1.f / (1.f + expf(-gf));
    float so = 1.f / (1.f + expf(-go));
    float cn = sf * cl[gl][o] + si * tanhf(gg);
    float hn = so * tanhf(cn);
    c[b * DIM + o] = cn;
    h[b * DIM + o] = hn;
    rnum[b * DIM + o] = 0.f;
    if (o == 0) { denom[b] = 0.f; emax[b] = 0x007FFFFFu; }  // fenc(-inf)
}

// -------- Set2Set step 2: e[n] = dot(x[n], q[batch[n]]); segment max --------
__global__ __launch_bounds__(256) void s2s_e_kernel(
    const float* __restrict__ x, const float* __restrict__ q,
    const int* __restrict__ batch, float* __restrict__ evec,
    unsigned* __restrict__ emax) {
    int t = blockIdx.x * 256 + threadIdx.x;
    int n = t >> 5, o = t & 31;
    if (n >= N_NODES) return;
    int b = batch[n];
    float p = x[n * DIM + o] * q[b * DIM + o];
    #pragma unroll
    for (int m = 16; m >= 1; m >>= 1) p += __shfl_xor(p, m, 32);
    if (o == 0) {
        evec[n] = p;
        atomicMax(&emax[b], fenc(p));
    }
}

// -------- Set2Set step 3: softmax accumulate --------
__global__ __launch_bounds__(256) void s2s_soft_kernel(
    const float* __restrict__ x, const int* __restrict__ batch,
    const float* __restrict__ evec, const unsigned* __restrict__ emax,
    float* __restrict__ rnum, float* __restrict__ denom) {
    int t = blockIdx.x * 256 + threadIdx.x;
    int n = t >> 5, o = t & 31;
    if (n >= N_NODES) return;
    int b = batch[n];
    float ex = expf(evec[n] - fdec(emax[b]));
    if (o == 0) atomicAdd(&denom[b], ex);
    atomicAdd(&rnum[b * DIM + o], ex * x[n * DIM + o]);
}

// -------- Set2Set step 4: q_star = [q, rnum/denom] --------
__global__ __launch_bounds__(256) void s2s_qstar_kernel(
    const float* __restrict__ h, const float* __restrict__ rnum,
    const float* __restrict__ denom, float* __restrict__ qstar) {
    int t = blockIdx.x * 256 + threadIdx.x;
    int b = t >> 6, j = t & 63;
    if (b >= N_GRAPHS) return;
    float v;
    if (j < 32) v = h[b * DIM + j];
    else {
        float d = denom[b];
        v = d > 0.f ? rnum[b * DIM + (j - 32)] / d : 0.f;
    }
    qstar[b * 64 + j] = v;
}

extern "C" void kernel_launch(void* const* d_in, const int* in_sizes, int n_in,
                              void* d_out, int out_size, void* d_ws, size_t ws_size,
                              hipStream_t stream) {
    const float* nf   = (const float*)d_in[0];
    const float* ef   = (const float*)d_in[1];
    const float* l0w  = (const float*)d_in[2];
    const float* l0b  = (const float*)d_in[3];
    const float* w1   = (const float*)d_in[4];
    const float* b1   = (const float*)d_in[5];
    const float* w2   = (const float*)d_in[6];
    const float* b2   = (const float*)d_in[7];
    const float* cb   = (const float*)d_in[8];
    const float* gwih = (const float*)d_in[9];
    const float* gwhh = (const float*)d_in[10];
    const float* gbih = (const float*)d_in[11];
    const float* gbhh = (const float*)d_in[12];
    const float* lwih = (const float*)d_in[13];
    const float* lwhh = (const float*)d_in[14];
    const float* lbih = (const float*)d_in[15];
    const float* lbhh = (const float*)d_in[16];
    const int*   eidx = (const int*)d_in[17];
    const int*   gidx = (const int*)d_in[18];
    const int* src = eidx;
    const int* dst = eidx + N_EDGES;
    float* out = (float*)d_out;
    float* h   = out + (size_t)N_GRAPHS * 64;   // node state lives in d_out tail

    char* ws = (char*)d_ws;
    size_t off = 0;
    auto alloc = [&](size_t bytes) -> void* {
        void* p = ws + off;
        off = (off + bytes + 255) & ~(size_t)255;
        return p;
    };
    float* sbuf  = (float*)alloc((size_t)N_NODES * DIM * 4);   // 12.8 MB
    float* cnt   = (float*)alloc((size_t)N_NODES * 4);
    float* evec  = (float*)alloc((size_t)N_NODES * 4);
    float* hs    = (float*)alloc((size_t)N_GRAPHS * DIM * 4);
    float* cs    = (float*)alloc((size_t)N_GRAPHS * DIM * 4);
    float* qstar = (float*)alloc((size_t)N_GRAPHS * 64 * 4);
    float* rnum  = (float*)alloc((size_t)N_GRAPHS * DIM * 4);
    float* denom = (float*)alloc((size_t)N_GRAPHS * 4);
    unsigned* emax = (unsigned*)alloc((size_t)N_GRAPHS * 4);
    _Float16* w2f  = (_Float16*)alloc((size_t)W2F_HALFS * 2);  // 258 KB
    size_t fixed = off;
    size_t avail = ws_size > fixed ? ws_size - fixed : 0;

    // pick edge chunking so the fp16 frag-major hw buffer fits in remaining ws
    int nchunk = 1;
    auto need = [&](int nc) -> size_t {
        int cbk = (MSG_BLOCKS + nc - 1) / nc;
        return (size_t)cbk * 8 * 4096;   // 8 tiles/block * 4 KB/tile
    };
    while (nchunk < 64 && need(nchunk) > avail) nchunk <<= 1;
    int chunk_blocks = (MSG_BLOCKS + nchunk - 1) / nchunk;
    _Float16* hwf = (_Float16*)alloc(need(nchunk));

    // ---- prologue ----
    lin0_kernel<<<dim3((N_NODES + 7) / 8), dim3(256), 0, stream>>>(nf, l0w, l0b, h);
    prep_w2f_kernel<<<dim3((W2F_HALFS + 255) / 256), dim3(256), 0, stream>>>(w2, b2, w2f);
    hipMemsetAsync(cnt, 0, (size_t)N_NODES * 4, stream);
    cnt_kernel<<<dim3((N_EDGES + 255) / 256), dim3(256), 0, stream>>>(dst, cnt);
    if (nchunk == 1) {
        hw_kernel<<<dim3(MSG_BLOCKS * 64), dim3(256), 0, stream>>>(ef, w1, b1, hwf, 0);
    }

    // ---- 3 message-passing + GRU iterations ----
    for (int it = 0; it < 3; ++it) {
        hipMemsetAsync(sbuf, 0, (size_t)N_NODES * DIM * 4, stream);
        for (int c = 0; c < nchunk; ++c) {
            int bstart = c * chunk_blocks;
            int bc = MSG_BLOCKS - bstart;
            if (bc <= 0) break;
            if (bc > chunk_blocks) bc = chunk_blocks;
            int e_off = bstart * 128;
            if (nchunk > 1)
                hw_kernel<<<dim3(bc * 64), dim3(256), 0, stream>>>(ef, w1, b1, hwf, e_off);
            msg_kernel<<<dim3(bc), dim3(128), 0, stream>>>(hwf, w2f, h, src, dst, sbuf, e_off);
        }
        gru_kernel<<<dim3((N_NODES + 7) / 8), dim3(256), 0, stream>>>(
            sbuf, cnt, cb, gwih, gwhh, gbih, gbhh, h);
    }

    // ---- Set2Set ----
    hipMemsetAsync(hs, 0, (size_t)N_GRAPHS * DIM * 4, stream);
    hipMemsetAsync(cs, 0, (size_t)N_GRAPHS * DIM * 4, stream);
    hipMemsetAsync(qstar, 0, (size_t)N_GRAPHS * 64 * 4, stream);
    for (int st = 0; st < 3; ++st) {
        s2s_lstm_kernel<<<dim3(N_GRAPHS / 8), dim3(256), 0, stream>>>(
            qstar, lwih, lwhh, lbih, lbhh, hs, cs, rnum, denom, emax);
        s2s_e_kernel<<<dim3((N_NODES * 32 + 255) / 256), dim3(256), 0, stream>>>(
            h, hs, gidx, evec, emax);
        s2s_soft_kernel<<<dim3((N_NODES * 32 + 255) / 256), dim3(256), 0, stream>>>(
            h, gidx, evec, emax, rnum, denom);
        s2s_qstar_kernel<<<dim3((N_GRAPHS * 64 + 255) / 256), dim3(256), 0, stream>>>(
            hs, rnum, denom, qstar);
    }
    // pooled output -> d_out head (h already in place in d_out tail)
    hipMemcpyAsync(out, qstar, (size_t)N_GRAPHS * 64 * 4, hipMemcpyDeviceToDevice, stream);
}

// Round 3
// 1081.308 us; speedup vs baseline: 1.9569x; 1.9569x over previous
//
#include <hip/hip_runtime.h>
#include <stdint.h>

#define N_NODES  100000
#define N_EDGES  250000
#define N_GRAPHS 2000
#define F_IN     75
#define DIM      32
#define H1       128

#define MSG_BLOCKS 977           // ceil(250000/256), 256 edges per msg block
#define KT_REAL   129            // 128 kt of W2 + 1 kt of b2 fold-in
#define CH        8              // kt per LDS stage (16 KB)
#define NSTAGES   17
#define KT_PAD    (CH * NSTAGES) // 136, padded with zeros
#define W2F_HALFS (KT_PAD * 1024)

typedef _Float16 v8h __attribute__((ext_vector_type(8)));
typedef float    v4f __attribute__((ext_vector_type(4)));

// order-preserving float->uint encoding for atomicMax
__device__ __forceinline__ unsigned fenc(float f) {
    unsigned u = __float_as_uint(f);
    return (u & 0x80000000u) ? ~u : (u | 0x80000000u);
}
__device__ __forceinline__ float fdec(unsigned e) {
    unsigned u = (e & 0x80000000u) ? (e & 0x7FFFFFFFu) : ~e;
    return __uint_as_float(u);
}

__device__ __forceinline__ void gld_lds16(const void* g, void* l) {
    __builtin_amdgcn_global_load_lds(
        (const __attribute__((address_space(1))) unsigned int*)g,
        (__attribute__((address_space(3))) unsigned int*)l, 16, 0, 0);
}

// -------- lin0: h = relu(nf @ W.T + b), 32 nodes/block --------
__global__ __launch_bounds__(256) void lin0_kernel(
    const float* __restrict__ nf, const float* __restrict__ w,
    const float* __restrict__ b, float* __restrict__ h) {
    __shared__ float wl[DIM * F_IN];
    __shared__ float bl[DIM];
    int t = threadIdx.x;
    for (int i = t; i < DIM * F_IN; i += 256) wl[i] = w[i];
    if (t < DIM) bl[t] = b[t];
    __syncthreads();
    int nl = t >> 5, o = t & 31;
    #pragma unroll
    for (int p = 0; p < 4; ++p) {
        int n = blockIdx.x * 32 + p * 8 + nl;
        if (n >= N_NODES) continue;
        const float* row = nf + (size_t)n * F_IN;
        float acc = bl[o];
        #pragma unroll
        for (int i = 0; i < F_IN; ++i) acc += row[i] * wl[o * F_IN + i];
        h[n * DIM + o] = fmaxf(acc, 0.f);
    }
}

// -------- build W2t fragment-major fp16 table (+ b2 as kt=128, zeros beyond) --------
__global__ __launch_bounds__(256) void prep_w2f_kernel(
    const float* __restrict__ w2, const float* __restrict__ b2,
    _Float16* __restrict__ w2f) {
    int id = blockIdx.x * 256 + threadIdx.x;
    if (id >= W2F_HALFS) return;
    int j    = id & 7;
    int lane = (id >> 3) & 63;
    int ng   = (id >> 9) & 1;
    int kt   = id >> 10;
    int lr = lane & 15, q = lane >> 4;
    int c = kt * 32 + q * 8 + j;
    int o = ng * 16 + lr;
    float val = 0.f;
    if (c < 4096)      val = w2[((c >> 7) * 32 + o) * H1 + (c & 127)];
    else if (c < 4128) val = b2[(c - 4096) * 32 + o];
    w2f[id] = (_Float16)val;
}

// -------- edge hidden hw = relu(ef @ W1.T + b1), fp16 FRAG-MAJOR, 32 edges/block --------
__global__ __launch_bounds__(256) void hw_kernel(
    const float* __restrict__ ef, const float* __restrict__ w1,
    const float* __restrict__ b1, _Float16* __restrict__ hwf,
    int e_off) {
    __shared__ float wl[H1 * 11];
    __shared__ float bl[H1];
    int t = threadIdx.x;
    for (int i = t; i < H1 * 11; i += 256) wl[i] = w1[i];
    if (t < H1) bl[t] = b1[t];
    __syncthreads();
    int k = t & 127;
    #pragma unroll
    for (int p = 0; p < 16; ++p) {
        int le = blockIdx.x * 32 + p * 2 + (t >> 7);
        int e  = e_off + le;
        float acc = 0.f;
        if (e < N_EDGES) {
            const float* row = ef + (size_t)e * 11;
            acc = bl[k];
            #pragma unroll
            for (int i = 0; i < 11; ++i) acc += row[i] * wl[k * 11 + i];
            acc = fmaxf(acc, 0.f);
        }
        size_t addr = (size_t)(le >> 4) * 2048 + (k >> 3) * 128 + (le & 15) * 8 + (k & 7);
        hwf[addr] = (_Float16)acc;
    }
}

// -------- in-degree counts --------
__global__ __launch_bounds__(256) void cnt_kernel(
    const int* __restrict__ dst, float* __restrict__ cnt) {
    int e = blockIdx.x * 256 + threadIdx.x;
    if (e < N_EDGES) atomicAdd(&cnt[dst[e]], 1.0f);
}

// -------- fused message GEMM: msg = (x[src] (x) hw) @ W2t, LDS-staged B --------
// 256 threads = 4 waves, 256 edges/block; B double-buffered via global_load_lds
__global__ __launch_bounds__(256) void msg_kernel(
    const _Float16* __restrict__ hwf, const _Float16* __restrict__ w2f,
    const float* __restrict__ x, const int* __restrict__ src,
    const int* __restrict__ dst, float* __restrict__ sbuf, int e_off) {
    __shared__ _Float16 xs[32 * 256];        // 16 KB: xs[i][e_loc]
    __shared__ _Float16 bst[2][CH * 1024];   // 2 x 16 KB B stages

    int t = threadIdx.x;
    int w = t >> 6, lane = t & 63, lr = lane & 15, q = lane >> 4;
    int wbase = w * 64;

    // issue stage-0 B prefetch (16 KB, 4 x 256-thread x 16 B)
    {
        const char* gp = (const char*)w2f;
        char* lp = (char*)&bst[0][0];
        #pragma unroll
        for (int it = 0; it < 4; ++it)
            gld_lds16(gp + it * 4096 + t * 16, lp + it * 4096 + t * 16);
    }

    // preload hw fragments for this wave's 64 edges (coalesced 1 KB/wave reads)
    v8h hwr[4][4];
    {
        const v8h* hv = (const v8h*)hwf;
        int T0 = blockIdx.x * 16 + w * 4;
        #pragma unroll
        for (int mt = 0; mt < 4; ++mt)
            #pragma unroll
            for (int kc = 0; kc < 4; ++kc)
                hwr[mt][kc] = hv[(size_t)(T0 + mt) * 256 + (kc * 4 + q) * 16 + lr];
    }

    // stage x[src] (fp32 -> fp16)
    {
        int e = e_off + blockIdx.x * 256 + t;
        int ec = e < N_EDGES ? e : N_EDGES - 1;
        int sv = src[ec];
        const float4* xr = (const float4*)(x + (size_t)sv * DIM);
        #pragma unroll
        for (int u = 0; u < 8; ++u) {
            float4 v = xr[u];
            xs[(u * 4 + 0) * 256 + t] = (_Float16)v.x;
            xs[(u * 4 + 1) * 256 + t] = (_Float16)v.y;
            xs[(u * 4 + 2) * 256 + t] = (_Float16)v.z;
            xs[(u * 4 + 3) * 256 + t] = (_Float16)v.w;
        }
    }
    __syncthreads();   // stage 0 + xs ready (barrier drains vmcnt)

    v4f acc[4][2];
    #pragma unroll
    for (int mt = 0; mt < 4; ++mt)
        #pragma unroll
        for (int ng = 0; ng < 2; ++ng) { v4f z = {0.f, 0.f, 0.f, 0.f}; acc[mt][ng] = z; }

    _Float16 xsc[4];

    for (int s = 0; s < NSTAGES - 1; ++s) {
        // prefetch next stage into other buffer
        {
            const char* gp = (const char*)(w2f + (size_t)(s + 1) * CH * 1024);
            char* lp = (char*)&bst[(s + 1) & 1][0];
            #pragma unroll
            for (int it = 0; it < 4; ++it)
                gld_lds16(gp + it * 4096 + t * 16, lp + it * 4096 + t * 16);
        }
        const _Float16* bb = &bst[s & 1][0];
        #pragma unroll
        for (int ktl = 0; ktl < CH; ++ktl) {
            int kt = s * CH + ktl;
            v8h b0 = *(const v8h*)(bb + ktl * 1024 + lane * 8);
            v8h b1 = *(const v8h*)(bb + ktl * 1024 + 512 + lane * 8);
            if ((kt & 3) == 0) {
                int i = kt >> 2;
                #pragma unroll
                for (int mt = 0; mt < 4; ++mt)
                    xsc[mt] = xs[i * 256 + wbase + mt * 16 + lr];
            }
            int kc = kt & 3;
            #pragma unroll
            for (int mt = 0; mt < 4; ++mt) {
                v8h a = hwr[mt][kc] * xsc[mt];
                acc[mt][0] = __builtin_amdgcn_mfma_f32_16x16x32_f16(a, b0, acc[mt][0], 0, 0, 0);
                acc[mt][1] = __builtin_amdgcn_mfma_f32_16x16x32_f16(a, b1, acc[mt][1], 0, 0, 0);
            }
        }
        __syncthreads();  // all waves done with buf s; load of s+1 drained
    }
    // final stage (s=16, buf 0): only kt=128 is real (bias fold-in); kt>128 are zero B
    {
        const _Float16* bb = &bst[0][0];
        v8h b0 = *(const v8h*)(bb + lane * 8);
        v8h b1 = *(const v8h*)(bb + 512 + lane * 8);
        #pragma unroll
        for (int mt = 0; mt < 4; ++mt) {
            v8h a;
            #pragma unroll
            for (int j = 0; j < 8; ++j)
                a[j] = xs[(q * 8 + j) * 256 + wbase + mt * 16 + lr];
            acc[mt][0] = __builtin_amdgcn_mfma_f32_16x16x32_f16(a, b0, acc[mt][0], 0, 0, 0);
            acc[mt][1] = __builtin_amdgcn_mfma_f32_16x16x32_f16(a, b1, acc[mt][1], 0, 0, 0);
        }
    }

    // epilogue: D[m = q*4+r][n = lr]; scatter-add to sbuf[dst]
    int E0 = e_off + blockIdx.x * 256 + wbase;
    #pragma unroll
    for (int mt = 0; mt < 4; ++mt) {
        #pragma unroll
        for (int r = 0; r < 4; ++r) {
            int e = E0 + mt * 16 + q * 4 + r;
            if (e < N_EDGES) {
                int dv = dst[e];
                float* sp = sbuf + (size_t)dv * DIM;
                atomicAdd(sp + lr,      acc[mt][0][r]);
                atomicAdd(sp + 16 + lr, acc[mt][1][r]);
            }
        }
    }
}

// -------- fused scatter-mean finalize + conv_bias + relu + GRU cell, 32 nodes/block --------
__global__ __launch_bounds__(256) void gru_kernel(
    const float* __restrict__ s, const float* __restrict__ cnt,
    const float* __restrict__ cb,
    const float* __restrict__ wih, const float* __restrict__ whh,
    const float* __restrict__ bih, const float* __restrict__ bhh,
    float* __restrict__ h) {
    __shared__ float wi[96 * 33], wh[96 * 33];
    __shared__ float bi[96], bh[96], cbl[DIM];
    int t = threadIdx.x;
    for (int i = t; i < 96 * DIM; i += 256) {
        int r = i >> 5, c = i & 31;
        wi[r * 33 + c] = wih[i];
        wh[r * 33 + c] = whh[i];
    }
    if (t < 96) { bi[t] = bih[t]; bh[t] = bhh[t]; }
    if (t < DIM) cbl[t] = cb[t];
    __syncthreads();
    int nl = t >> 5, o = t & 31;
    #pragma unroll
    for (int p = 0; p < 4; ++p) {
        int n = blockIdx.x * 32 + p * 8 + nl;   // uniform across each 32-lane group
        if (n >= N_NODES) continue;
        float c = cnt[n];
        c = c > 1.f ? c : 1.f;
        float m  = fmaxf(s[n * DIM + o] / c + cbl[o], 0.f);
        float hv0 = h[n * DIM + o];
        float gir = bi[o],      giz = bi[32 + o], gin = bi[64 + o];
        float ghr = bh[o],      ghz = bh[32 + o], ghn = bh[64 + o];
        #pragma unroll
        for (int i = 0; i < DIM; ++i) {
            float mv = __shfl(m, i, 32);
            float hv = __shfl(hv0, i, 32);
            gir += mv * wi[o * 33 + i];
            giz += mv * wi[(32 + o) * 33 + i];
            gin += mv * wi[(64 + o) * 33 + i];
            ghr += hv * wh[o * 33 + i];
            ghz += hv * wh[(32 + o) * 33 + i];
            ghn += hv * wh[(64 + o) * 33 + i];
        }
        float r  = 1.f / (1.f + expf(-(gir + ghr)));
        float z  = 1.f / (1.f + expf(-(giz + ghz)));
        float nn = tanhf(gin + r * ghn);
        h[n * DIM + o] = (1.f - z) * nn + z * hv0;
    }
}

// -------- Set2Set LSTM: builds q_star from (h, rnum, denom) inline; re-inits softmax accum --------
__global__ __launch_bounds__(256) void s2s_lstm_kernel(
    const float* __restrict__ wih, const float* __restrict__ whh,
    const float* __restrict__ bih, const float* __restrict__ bhh,
    float* __restrict__ h, float* __restrict__ c,
    float* __restrict__ rnum, float* __restrict__ denom,
    unsigned* __restrict__ emax, int first) {
    // wA = wih[:, :32] + whh (h input == q == q_star[:32]); wB = wih[:, 32:]
    __shared__ float wA[128 * 33], wB[128 * 33], bl[128];
    int t = threadIdx.x;
    for (int i = t; i < 128 * 32; i += 256) {
        int r = i >> 5, cc = i & 31;
        wA[r * 33 + cc] = wih[r * 64 + cc] + whh[r * 32 + cc];
        wB[r * 33 + cc] = wih[r * 64 + 32 + cc];
    }
    if (t < 128) bl[t] = bih[t] + bhh[t];
    __syncthreads();
    int gl = t >> 5, o = t & 31;
    int b = blockIdx.x * 8 + gl;
    if (b >= N_GRAPHS) return;
    float hq = 0.f, rr = 0.f, cv = 0.f;
    if (!first) {
        hq = h[b * DIM + o];
        float d = denom[b];
        rr = d > 0.f ? rnum[b * DIM + o] / d : 0.f;
        cv = c[b * DIM + o];
    }
    float gi = bl[o], gf = bl[32 + o], gg = bl[64 + o], go = bl[96 + o];
    #pragma unroll
    for (int i = 0; i < 32; ++i) {
        float qv = __shfl(hq, i, 32);
        float rv = __shfl(rr, i, 32);
        gi += qv * wA[o * 33 + i]        + rv * wB[o * 33 + i];
        gf += qv * wA[(32 + o) * 33 + i] + rv * wB[(32 + o) * 33 + i];
        gg += qv * wA[(64 + o) * 33 + i] + rv * wB[(64 + o) * 33 + i];
        go += qv * wA[(96 + o) * 33 + i] + rv * wB[(96 + o) * 33 + i];
    }
    float si = 1.f / (1.f + expf(-gi));
    float sf = 1.f / (1.f + expf(-gf));
    float so = 1.f / (1.f + expf(-go));
    float cn = sf * cv + si * tanhf(gg);
    c[b * DIM + o] = cn;
    h[b * DIM + o] = so * tanhf(cn);
    rnum[b * DIM + o] = 0.f;
    if (o == 0) { denom[b] = 0.f; emax[b] = 0x007FFFFFu; }  // fenc(-inf)
}

// -------- Set2Set: e[n] = dot(x[n], q[batch[n]]); segment max --------
__global__ __launch_bounds__(256) void s2s_e_kernel(
    const float* __restrict__ x, const float* __restrict__ q,
    const int* __restrict__ batch, float* __restrict__ evec,
    unsigned* __restrict__ emax) {
    int t = blockIdx.x * 256 + threadIdx.x;
    int n = t >> 5, o = t & 31;
    if (n >= N_NODES) return;
    int b = batch[n];
    float p = x[n * DIM + o] * q[b * DIM + o];
    #pragma unroll
    for (int m = 16; m >= 1; m >>= 1) p += __shfl_xor(p, m, 32);
    if (o == 0) {
        evec[n] = p;
        atomicMax(&emax[b], fenc(p));
    }
}

// -------- Set2Set: softmax accumulate --------
__global__ __launch_bounds__(256) void s2s_soft_kernel(
    const float* __restrict__ x, const int* __restrict__ batch,
    const float* __restrict__ evec, const unsigned* __restrict__ emax,
    float* __restrict__ rnum, float* __restrict__ denom) {
    int t = blockIdx.x * 256 + threadIdx.x;
    int n = t >> 5, o = t & 31;
    if (n >= N_NODES) return;
    int b = batch[n];
    float ex = expf(evec[n] - fdec(emax[b]));
    if (o == 0) atomicAdd(&denom[b], ex);
    atomicAdd(&rnum[b * DIM + o], ex * x[n * DIM + o]);
}

// -------- final pooled output: out[b] = [q, rnum/denom] --------
__global__ __launch_bounds__(256) void pooled_kernel(
    const float* __restrict__ h, const float* __restrict__ rnum,
    const float* __restrict__ denom, float* __restrict__ out) {
    int t = blockIdx.x * 256 + threadIdx.x;
    int b = t >> 6, j = t & 63;
    if (b >= N_GRAPHS) return;
    float v;
    if (j < 32) v = h[b * DIM + j];
    else {
        float d = denom[b];
        v = d > 0.f ? rnum[b * DIM + (j - 32)] / d : 0.f;
    }
    out[b * 64 + j] = v;
}

extern "C" void kernel_launch(void* const* d_in, const int* in_sizes, int n_in,
                              void* d_out, int out_size, void* d_ws, size_t ws_size,
                              hipStream_t stream) {
    const float* nf   = (const float*)d_in[0];
    const float* ef   = (const float*)d_in[1];
    const float* l0w  = (const float*)d_in[2];
    const float* l0b  = (const float*)d_in[3];
    const float* w1   = (const float*)d_in[4];
    const float* b1   = (const float*)d_in[5];
    const float* w2   = (const float*)d_in[6];
    const float* b2   = (const float*)d_in[7];
    const float* cb   = (const float*)d_in[8];
    const float* gwih = (const float*)d_in[9];
    const float* gwhh = (const float*)d_in[10];
    const float* gbih = (const float*)d_in[11];
    const float* gbhh = (const float*)d_in[12];
    const float* lwih = (const float*)d_in[13];
    const float* lwhh = (const float*)d_in[14];
    const float* lbih = (const float*)d_in[15];
    const float* lbhh = (const float*)d_in[16];
    const int*   eidx = (const int*)d_in[17];
    const int*   gidx = (const int*)d_in[18];
    const int* src = eidx;
    const int* dst = eidx + N_EDGES;
    float* out = (float*)d_out;
    float* h   = out + (size_t)N_GRAPHS * 64;   // node state lives in d_out tail

    char* ws = (char*)d_ws;
    size_t off = 0;
    auto alloc = [&](size_t bytes) -> void* {
        void* p = ws + off;
        off = (off + bytes + 255) & ~(size_t)255;
        return p;
    };
    float* sbuf  = (float*)alloc((size_t)N_NODES * DIM * 4);   // 12.8 MB
    float* cnt   = (float*)alloc((size_t)N_NODES * 4);
    float* evec  = (float*)alloc((size_t)N_NODES * 4);
    float* hs    = (float*)alloc((size_t)N_GRAPHS * DIM * 4);
    float* cs    = (float*)alloc((size_t)N_GRAPHS * DIM * 4);
    float* rnum  = (float*)alloc((size_t)N_GRAPHS * DIM * 4);
    float* denom = (float*)alloc((size_t)N_GRAPHS * 4);
    unsigned* emax = (unsigned*)alloc((size_t)N_GRAPHS * 4);
    _Float16* w2f  = (_Float16*)alloc((size_t)W2F_HALFS * 2);  // 272 KB
    size_t fixed = off;
    size_t avail = ws_size > fixed ? ws_size - fixed : 0;

    // pick edge chunking so the fp16 frag-major hw buffer fits in remaining ws
    auto need = [&](int nc) -> size_t {
        int cbk = (MSG_BLOCKS + nc - 1) / nc;
        return (size_t)cbk * 16 * 4096;   // 16 tiles/block * 4 KB/tile
    };
    int nchunk = 1;
    while (nchunk < 64 && need(nchunk) > avail) nchunk <<= 1;
    int chunk_blocks = (MSG_BLOCKS + nchunk - 1) / nchunk;
    _Float16* hwf = (_Float16*)alloc(need(nchunk));

    // ---- prologue ----
    lin0_kernel<<<dim3((N_NODES + 31) / 32), dim3(256), 0, stream>>>(nf, l0w, l0b, h);
    prep_w2f_kernel<<<dim3((W2F_HALFS + 255) / 256), dim3(256), 0, stream>>>(w2, b2, w2f);
    hipMemsetAsync(cnt, 0, (size_t)N_NODES * 4, stream);
    cnt_kernel<<<dim3((N_EDGES + 255) / 256), dim3(256), 0, stream>>>(dst, cnt);
    if (nchunk == 1) {
        hw_kernel<<<dim3(MSG_BLOCKS * 8), dim3(256), 0, stream>>>(ef, w1, b1, hwf, 0);
    }

    // ---- 3 message-passing + GRU iterations ----
    for (int it = 0; it < 3; ++it) {
        hipMemsetAsync(sbuf, 0, (size_t)N_NODES * DIM * 4, stream);
        for (int cix = 0; cix < nchunk; ++cix) {
            int bstart = cix * chunk_blocks;
            int bc = MSG_BLOCKS - bstart;
            if (bc <= 0) break;
            if (bc > chunk_blocks) bc = chunk_blocks;
            int e_off = bstart * 256;
            if (nchunk > 1)
                hw_kernel<<<dim3(bc * 8), dim3(256), 0, stream>>>(ef, w1, b1, hwf, e_off);
            msg_kernel<<<dim3(bc), dim3(256), 0, stream>>>(hwf, w2f, h, src, dst, sbuf, e_off);
        }
        gru_kernel<<<dim3((N_NODES + 31) / 32), dim3(256), 0, stream>>>(
            sbuf, cnt, cb, gwih, gwhh, gbih, gbhh, h);
    }

    // ---- Set2Set (h/c/rnum/denom initialized via `first` path) ----
    for (int st = 0; st < 3; ++st) {
        s2s_lstm_kernel<<<dim3((N_GRAPHS + 7) / 8), dim3(256), 0, stream>>>(
            lwih, lwhh, lbih, lbhh, hs, cs, rnum, denom, emax, st == 0 ? 1 : 0);
        s2s_e_kernel<<<dim3((N_NODES * 32 + 255) / 256), dim3(256), 0, stream>>>(
            h, hs, gidx, evec, emax);
        s2s_soft_kernel<<<dim3((N_NODES * 32 + 255) / 256), dim3(256), 0, stream>>>(
            h, gidx, evec, emax, rnum, denom);
    }
    pooled_kernel<<<dim3((N_GRAPHS * 64 + 255) / 256), dim3(256), 0, stream>>>(
        hs, rnum, denom, out);
}

// Round 4
// 882.901 us; speedup vs baseline: 2.3967x; 1.2247x over previous
//
#include <hip/hip_runtime.h>
#include <stdint.h>

#define N_NODES  100000
#define N_EDGES  250000
#define N_GRAPHS 2000
#define F_IN     75
#define DIM      32
#define H1       128

#define MSG_BLOCKS 977           // ceil(250000/256), 256 edges per msg block
#define CH        8              // kt per LDS stage (16 KB)
#define NSTAGES   17
#define KT_PAD    (CH * NSTAGES) // 136, padded with zeros
#define W2F_HALFS (KT_PAD * 1024)

#define S2S_NB    1024           // nodes per s2s block
#define S2S_G     96             // max graph span per s2s block (LDS path)

typedef _Float16 v8h __attribute__((ext_vector_type(8)));
typedef float    v4f __attribute__((ext_vector_type(4)));

// order-preserving float->uint encoding for atomicMax
__device__ __forceinline__ unsigned fenc(float f) {
    unsigned u = __float_as_uint(f);
    return (u & 0x80000000u) ? ~u : (u | 0x80000000u);
}
__device__ __forceinline__ float fdec(unsigned e) {
    unsigned u = (e & 0x80000000u) ? (e & 0x7FFFFFFFu) : ~e;
    return __uint_as_float(u);
}

__device__ __forceinline__ void gld_lds16(const void* g, void* l) {
    __builtin_amdgcn_global_load_lds(
        (const __attribute__((address_space(1))) unsigned int*)g,
        (__attribute__((address_space(3))) unsigned int*)l, 16, 0, 0);
}

// -------- lin0: h = relu(nf @ W.T + b), 32 nodes/block --------
__global__ __launch_bounds__(256) void lin0_kernel(
    const float* __restrict__ nf, const float* __restrict__ w,
    const float* __restrict__ b, float* __restrict__ h) {
    __shared__ float wl[DIM * F_IN];
    __shared__ float bl[DIM];
    int t = threadIdx.x;
    for (int i = t; i < DIM * F_IN; i += 256) wl[i] = w[i];
    if (t < DIM) bl[t] = b[t];
    __syncthreads();
    int nl = t >> 5, o = t & 31;
    #pragma unroll
    for (int p = 0; p < 4; ++p) {
        int n = blockIdx.x * 32 + p * 8 + nl;
        if (n >= N_NODES) continue;
        const float* row = nf + (size_t)n * F_IN;
        float acc = bl[o];
        #pragma unroll
        for (int i = 0; i < F_IN; ++i) acc += row[i] * wl[o * F_IN + i];
        h[n * DIM + o] = fmaxf(acc, 0.f);
    }
}

// -------- build W2t fragment-major fp16 table (+ b2 as kt=128, zeros beyond) --------
__global__ __launch_bounds__(256) void prep_w2f_kernel(
    const float* __restrict__ w2, const float* __restrict__ b2,
    _Float16* __restrict__ w2f) {
    int id = blockIdx.x * 256 + threadIdx.x;
    if (id >= W2F_HALFS) return;
    int j    = id & 7;
    int lane = (id >> 3) & 63;
    int ng   = (id >> 9) & 1;
    int kt   = id >> 10;
    int lr = lane & 15, q = lane >> 4;
    int c = kt * 32 + q * 8 + j;
    int o = ng * 16 + lr;
    float val = 0.f;
    if (c < 4096)      val = w2[((c >> 7) * 32 + o) * H1 + (c & 127)];
    else if (c < 4128) val = b2[(c - 4096) * 32 + o];
    w2f[id] = (_Float16)val;
}

// -------- edge hidden hw = relu(ef @ W1.T + b1), fp16 FRAG-MAJOR, 32 edges/block --------
__global__ __launch_bounds__(256) void hw_kernel(
    const float* __restrict__ ef, const float* __restrict__ w1,
    const float* __restrict__ b1, _Float16* __restrict__ hwf,
    int e_off) {
    __shared__ float wl[H1 * 11];
    __shared__ float bl[H1];
    int t = threadIdx.x;
    for (int i = t; i < H1 * 11; i += 256) wl[i] = w1[i];
    if (t < H1) bl[t] = b1[t];
    __syncthreads();
    int k = t & 127;
    #pragma unroll
    for (int p = 0; p < 16; ++p) {
        int le = blockIdx.x * 32 + p * 2 + (t >> 7);
        int e  = e_off + le;
        float acc = 0.f;
        if (e < N_EDGES) {
            const float* row = ef + (size_t)e * 11;
            acc = bl[k];
            #pragma unroll
            for (int i = 0; i < 11; ++i) acc += row[i] * wl[k * 11 + i];
            acc = fmaxf(acc, 0.f);
        }
        size_t addr = (size_t)(le >> 4) * 2048 + (k >> 3) * 128 + (le & 15) * 8 + (k & 7);
        hwf[addr] = (_Float16)acc;
    }
}

// -------- in-degree counts --------
__global__ __launch_bounds__(256) void cnt_kernel(
    const int* __restrict__ dst, float* __restrict__ cnt) {
    int e = blockIdx.x * 256 + threadIdx.x;
    if (e < N_EDGES) atomicAdd(&cnt[dst[e]], 1.0f);
}

// -------- fused message GEMM: msg = (x[src] (x) hw) @ W2t, LDS-staged B --------
__global__ __launch_bounds__(256) void msg_kernel(
    const _Float16* __restrict__ hwf, const _Float16* __restrict__ w2f,
    const float* __restrict__ x, const int* __restrict__ src,
    const int* __restrict__ dst, float* __restrict__ sbuf, int e_off) {
    __shared__ _Float16 xs[32 * 256];        // 16 KB: xs[i][e_loc]
    __shared__ _Float16 bst[2][CH * 1024];   // 2 x 16 KB B stages

    int t = threadIdx.x;
    int w = t >> 6, lane = t & 63, lr = lane & 15, q = lane >> 4;
    int wbase = w * 64;

    {
        const char* gp = (const char*)w2f;
        char* lp = (char*)&bst[0][0];
        #pragma unroll
        for (int it = 0; it < 4; ++it)
            gld_lds16(gp + it * 4096 + t * 16, lp + it * 4096 + t * 16);
    }

    v8h hwr[4][4];
    {
        const v8h* hv = (const v8h*)hwf;
        int T0 = blockIdx.x * 16 + w * 4;
        #pragma unroll
        for (int mt = 0; mt < 4; ++mt)
            #pragma unroll
            for (int kc = 0; kc < 4; ++kc)
                hwr[mt][kc] = hv[(size_t)(T0 + mt) * 256 + (kc * 4 + q) * 16 + lr];
    }

    {
        int e = e_off + blockIdx.x * 256 + t;
        int ec = e < N_EDGES ? e : N_EDGES - 1;
        int sv = src[ec];
        const float4* xr = (const float4*)(x + (size_t)sv * DIM);
        #pragma unroll
        for (int u = 0; u < 8; ++u) {
            float4 v = xr[u];
            xs[(u * 4 + 0) * 256 + t] = (_Float16)v.x;
            xs[(u * 4 + 1) * 256 + t] = (_Float16)v.y;
            xs[(u * 4 + 2) * 256 + t] = (_Float16)v.z;
            xs[(u * 4 + 3) * 256 + t] = (_Float16)v.w;
        }
    }
    __syncthreads();

    v4f acc[4][2];
    #pragma unroll
    for (int mt = 0; mt < 4; ++mt)
        #pragma unroll
        for (int ng = 0; ng < 2; ++ng) { v4f z = {0.f, 0.f, 0.f, 0.f}; acc[mt][ng] = z; }

    _Float16 xsc[4];

    for (int s = 0; s < NSTAGES - 1; ++s) {
        {
            const char* gp = (const char*)(w2f + (size_t)(s + 1) * CH * 1024);
            char* lp = (char*)&bst[(s + 1) & 1][0];
            #pragma unroll
            for (int it = 0; it < 4; ++it)
                gld_lds16(gp + it * 4096 + t * 16, lp + it * 4096 + t * 16);
        }
        const _Float16* bb = &bst[s & 1][0];
        #pragma unroll
        for (int ktl = 0; ktl < CH; ++ktl) {
            int kt = s * CH + ktl;
            v8h b0 = *(const v8h*)(bb + ktl * 1024 + lane * 8);
            v8h b1 = *(const v8h*)(bb + ktl * 1024 + 512 + lane * 8);
            if ((kt & 3) == 0) {
                int i = kt >> 2;
                #pragma unroll
                for (int mt = 0; mt < 4; ++mt)
                    xsc[mt] = xs[i * 256 + wbase + mt * 16 + lr];
            }
            int kc = kt & 3;
            #pragma unroll
            for (int mt = 0; mt < 4; ++mt) {
                v8h a = hwr[mt][kc] * xsc[mt];
                acc[mt][0] = __builtin_amdgcn_mfma_f32_16x16x32_f16(a, b0, acc[mt][0], 0, 0, 0);
                acc[mt][1] = __builtin_amdgcn_mfma_f32_16x16x32_f16(a, b1, acc[mt][1], 0, 0, 0);
            }
        }
        __syncthreads();
    }
    {
        const _Float16* bb = &bst[0][0];
        v8h b0 = *(const v8h*)(bb + lane * 8);
        v8h b1 = *(const v8h*)(bb + 512 + lane * 8);
        #pragma unroll
        for (int mt = 0; mt < 4; ++mt) {
            v8h a;
            #pragma unroll
            for (int j = 0; j < 8; ++j)
                a[j] = xs[(q * 8 + j) * 256 + wbase + mt * 16 + lr];
            acc[mt][0] = __builtin_amdgcn_mfma_f32_16x16x32_f16(a, b0, acc[mt][0], 0, 0, 0);
            acc[mt][1] = __builtin_amdgcn_mfma_f32_16x16x32_f16(a, b1, acc[mt][1], 0, 0, 0);
        }
    }

    int E0 = e_off + blockIdx.x * 256 + wbase;
    #pragma unroll
    for (int mt = 0; mt < 4; ++mt) {
        #pragma unroll
        for (int r = 0; r < 4; ++r) {
            int e = E0 + mt * 16 + q * 4 + r;
            if (e < N_EDGES) {
                int dv = dst[e];
                float* sp = sbuf + (size_t)dv * DIM;
                atomicAdd(sp + lr,      acc[mt][0][r]);
                atomicAdd(sp + 16 + lr, acc[mt][1][r]);
            }
        }
    }
}

// -------- MFMA GRU: scatter-mean finalize + conv_bias + relu + GRU cell --------
// block = 256 threads (4 waves), 64 nodes; wave = 16 nodes; gi/gh via 12 MFMA.
__global__ __launch_bounds__(256) void gru_kernel(
    const float* __restrict__ s, const float* __restrict__ cnt,
    const float* __restrict__ cb,
    const float* __restrict__ wih, const float* __restrict__ whh,
    const float* __restrict__ bih, const float* __restrict__ bhh,
    float* __restrict__ h) {
    __shared__ _Float16 m_l[64 * 32];   // 4 KB
    __shared__ _Float16 h_l[64 * 32];   // 4 KB
    int t = threadIdx.x;

    // stage m = relu(s/cnt + cb) and h into LDS as fp16 (4 threads/node, 8 dims each)
    {
        int node_l = t >> 2, part = t & 3;
        int n = blockIdx.x * 64 + node_l;
        int nc = n < N_NODES ? n : N_NODES - 1;
        float c = cnt[nc];
        float rc = 1.f / (c > 1.f ? c : 1.f);
        const float4* s4 = (const float4*)(s + (size_t)nc * DIM + part * 8);
        float4 sa = s4[0], sb = s4[1];
        const float* cbp = cb + part * 8;
        v8h mv;
        mv[0] = (_Float16)fmaxf(sa.x * rc + cbp[0], 0.f);
        mv[1] = (_Float16)fmaxf(sa.y * rc + cbp[1], 0.f);
        mv[2] = (_Float16)fmaxf(sa.z * rc + cbp[2], 0.f);
        mv[3] = (_Float16)fmaxf(sa.w * rc + cbp[3], 0.f);
        mv[4] = (_Float16)fmaxf(sb.x * rc + cbp[4], 0.f);
        mv[5] = (_Float16)fmaxf(sb.y * rc + cbp[5], 0.f);
        mv[6] = (_Float16)fmaxf(sb.z * rc + cbp[6], 0.f);
        mv[7] = (_Float16)fmaxf(sb.w * rc + cbp[7], 0.f);
        *(v8h*)&m_l[node_l * 32 + part * 8] = mv;
        const float4* h4 = (const float4*)(h + (size_t)nc * DIM + part * 8);
        float4 ha = h4[0], hb = h4[1];
        v8h hv;
        hv[0] = (_Float16)ha.x; hv[1] = (_Float16)ha.y;
        hv[2] = (_Float16)ha.z; hv[3] = (_Float16)ha.w;
        hv[4] = (_Float16)hb.x; hv[5] = (_Float16)hb.y;
        hv[6] = (_Float16)hb.z; hv[7] = (_Float16)hb.w;
        *(v8h*)&h_l[node_l * 32 + part * 8] = hv;
    }

    int w = t >> 6, lane = t & 63, lr = lane & 15, q = lane >> 4;

    // B fragments (wih/whh rows as n, dims as k) + biases preloaded into C
    v8h bi6[6], bh6[6];
    v4f ai[6], ah[6];
    #pragma unroll
    for (int nt = 0; nt < 6; ++nt) {
        const float* wr = wih + (size_t)(nt * 16 + lr) * 32 + q * 8;
        float4 wa = *(const float4*)wr, wb = *(const float4*)(wr + 4);
        v8h bv;
        bv[0] = (_Float16)wa.x; bv[1] = (_Float16)wa.y;
        bv[2] = (_Float16)wa.z; bv[3] = (_Float16)wa.w;
        bv[4] = (_Float16)wb.x; bv[5] = (_Float16)wb.y;
        bv[6] = (_Float16)wb.z; bv[7] = (_Float16)wb.w;
        bi6[nt] = bv;
        const float* wr2 = whh + (size_t)(nt * 16 + lr) * 32 + q * 8;
        float4 ha2 = *(const float4*)wr2, hb2 = *(const float4*)(wr2 + 4);
        v8h bv2;
        bv2[0] = (_Float16)ha2.x; bv2[1] = (_Float16)ha2.y;
        bv2[2] = (_Float16)ha2.z; bv2[3] = (_Float16)ha2.w;
        bv2[4] = (_Float16)hb2.x; bv2[5] = (_Float16)hb2.y;
        bv2[6] = (_Float16)hb2.z; bv2[7] = (_Float16)hb2.w;
        bh6[nt] = bv2;
        float bii = bih[nt * 16 + lr], bhi = bhh[nt * 16 + lr];
        v4f ci = {bii, bii, bii, bii}; ai[nt] = ci;
        v4f chh = {bhi, bhi, bhi, bhi}; ah[nt] = chh;
    }

    __syncthreads();

    v8h ma = *(const v8h*)&m_l[(w * 16 + lr) * 32 + q * 8];
    v8h ha = *(const v8h*)&h_l[(w * 16 + lr) * 32 + q * 8];
    #pragma unroll
    for (int nt = 0; nt < 6; ++nt) {
        ai[nt] = __builtin_amdgcn_mfma_f32_16x16x32_f16(ma, bi6[nt], ai[nt], 0, 0, 0);
        ah[nt] = __builtin_amdgcn_mfma_f32_16x16x32_f16(ha, bh6[nt], ah[nt], 0, 0, 0);
    }

    // epilogue: lane holds (node = w*16 + q*4 + r, o = g*16 + lr)
    int nb = blockIdx.x * 64 + w * 16 + q * 4;
    #pragma unroll
    for (int g = 0; g < 2; ++g) {
        int o = g * 16 + lr;
        #pragma unroll
        for (int r = 0; r < 4; ++r) {
            int n2 = nb + r;
            if (n2 < N_NODES) {
                float rg = 1.f / (1.f + expf(-(ai[g][r]     + ah[g][r])));
                float zg = 1.f / (1.f + expf(-(ai[2 + g][r] + ah[2 + g][r])));
                float ng = tanhf(ai[4 + g][r] + rg * ah[4 + g][r]);
                float hold = h[(size_t)n2 * DIM + o];
                h[(size_t)n2 * DIM + o] = (1.f - zg) * ng + zg * hold;
            }
        }
    }
}

// -------- Set2Set LSTM: builds q_star from (h, rnum, denom) inline; re-inits softmax accum --------
__global__ __launch_bounds__(256) void s2s_lstm_kernel(
    const float* __restrict__ wih, const float* __restrict__ whh,
    const float* __restrict__ bih, const float* __restrict__ bhh,
    float* __restrict__ h, float* __restrict__ c,
    float* __restrict__ rnum, float* __restrict__ denom,
    unsigned* __restrict__ emax, int first) {
    __shared__ float wA[128 * 33], wB[128 * 33], bl[128];
    int t = threadIdx.x;
    for (int i = t; i < 128 * 32; i += 256) {
        int r = i >> 5, cc = i & 31;
        wA[r * 33 + cc] = wih[r * 64 + cc] + whh[r * 32 + cc];
        wB[r * 33 + cc] = wih[r * 64 + 32 + cc];
    }
    if (t < 128) bl[t] = bih[t] + bhh[t];
    __syncthreads();
    int gl = t >> 5, o = t & 31;
    int b = blockIdx.x * 8 + gl;
    if (b >= N_GRAPHS) return;
    float hq = 0.f, rr = 0.f, cv = 0.f;
    if (!first) {
        hq = h[b * DIM + o];
        float d = denom[b];
        rr = d > 0.f ? rnum[b * DIM + o] / d : 0.f;
        cv = c[b * DIM + o];
    }
    float gi = bl[o], gf = bl[32 + o], gg = bl[64 + o], go = bl[96 + o];
    #pragma unroll
    for (int i = 0; i < 32; ++i) {
        float qv = __shfl(hq, i, 32);
        float rv = __shfl(rr, i, 32);
        gi += qv * wA[o * 33 + i]        + rv * wB[o * 33 + i];
        gf += qv * wA[(32 + o) * 33 + i] + rv * wB[(32 + o) * 33 + i];
        gg += qv * wA[(64 + o) * 33 + i] + rv * wB[(64 + o) * 33 + i];
        go += qv * wA[(96 + o) * 33 + i] + rv * wB[(96 + o) * 33 + i];
    }
    float si = 1.f / (1.f + expf(-gi));
    float sf = 1.f / (1.f + expf(-gf));
    float so = 1.f / (1.f + expf(-go));
    float cn = sf * cv + si * tanhf(gg);
    c[b * DIM + o] = cn;
    h[b * DIM + o] = so * tanhf(cn);
    rnum[b * DIM + o] = 0.f;
    if (o == 0) { denom[b] = 0.f; emax[b] = 0x007FFFFFu; }  // fenc(-inf)
}

// -------- Set2Set: e = dot(x, q[batch]); per-block LDS segment max (gidx sorted) --------
__global__ __launch_bounds__(256) void s2s_dot_kernel(
    const float* __restrict__ x, const float* __restrict__ q,
    const int* __restrict__ batch, float* __restrict__ evec,
    unsigned* __restrict__ emax) {
    __shared__ unsigned mloc[S2S_G];
    int t = threadIdx.x;
    int n0 = blockIdx.x * S2S_NB;
    int last = n0 + S2S_NB - 1; if (last >= N_NODES) last = N_NODES - 1;
    int bmin = batch[n0];
    int span = batch[last] - bmin + 1;
    bool lds_path = (span <= S2S_G);
    if (lds_path) {
        for (int i = t; i < S2S_G; i += 256) mloc[i] = 0x007FFFFFu;
        __syncthreads();
    }
    int nl = t >> 5, o = t & 31;
    for (int p = 0; p < S2S_NB / 8; ++p) {
        int n = n0 + p * 8 + nl;
        if (n >= N_NODES) break;
        int b = batch[n];
        float pv = x[(size_t)n * DIM + o] * q[b * DIM + o];
        #pragma unroll
        for (int m = 16; m >= 1; m >>= 1) pv += __shfl_xor(pv, m, 32);
        if (o == 0) {
            evec[n] = pv;
            if (lds_path) atomicMax(&mloc[b - bmin], fenc(pv));
            else          atomicMax(&emax[b], fenc(pv));
        }
    }
    if (lds_path) {
        __syncthreads();
        for (int g = t; g < span; g += 256)
            atomicMax(&emax[bmin + g], mloc[g]);
    }
}

// -------- Set2Set: softmax accumulate with per-block LDS segment reduction --------
__global__ __launch_bounds__(256) void s2s_soft_kernel(
    const float* __restrict__ x, const int* __restrict__ batch,
    const float* __restrict__ evec, const unsigned* __restrict__ emax,
    float* __restrict__ rnum, float* __restrict__ denom) {
    __shared__ float rloc[S2S_G * 33];  // slot 32 = denom
    int t = threadIdx.x;
    int n0 = blockIdx.x * S2S_NB;
    int last = n0 + S2S_NB - 1; if (last >= N_NODES) last = N_NODES - 1;
    int bmin = batch[n0];
    int span = batch[last] - bmin + 1;
    bool lds_path = (span <= S2S_G);
    if (lds_path) {
        for (int i = t; i < S2S_G * 33; i += 256) rloc[i] = 0.f;
        __syncthreads();
    }
    int nl = t >> 5, o = t & 31;
    for (int p = 0; p < S2S_NB / 8; ++p) {
        int n = n0 + p * 8 + nl;
        if (n >= N_NODES) break;
        int b = batch[n];
        float ex = expf(evec[n] - fdec(emax[b]));
        float xo = x[(size_t)n * DIM + o];
        if (lds_path) {
            atomicAdd(&rloc[(b - bmin) * 33 + o], ex * xo);
            if (o == 0) atomicAdd(&rloc[(b - bmin) * 33 + 32], ex);
        } else {
            atomicAdd(&rnum[b * DIM + o], ex * xo);
            if (o == 0) atomicAdd(&denom[b], ex);
        }
    }
    if (lds_path) {
        __syncthreads();
        for (int idx = t; idx < span * 33; idx += 256) {
            int g = idx / 33, o2 = idx - g * 33;
            float v = rloc[idx];
            if (v != 0.f) {
                if (o2 == 32) atomicAdd(&denom[bmin + g], v);
                else          atomicAdd(&rnum[(bmin + g) * DIM + o2], v);
            }
        }
    }
}

// -------- final pooled output: out[b] = [q, rnum/denom] --------
__global__ __launch_bounds__(256) void pooled_kernel(
    const float* __restrict__ h, const float* __restrict__ rnum,
    const float* __restrict__ denom, float* __restrict__ out) {
    int t = blockIdx.x * 256 + threadIdx.x;
    int b = t >> 6, j = t & 63;
    if (b >= N_GRAPHS) return;
    float v;
    if (j < 32) v = h[b * DIM + j];
    else {
        float d = denom[b];
        v = d > 0.f ? rnum[b * DIM + (j - 32)] / d : 0.f;
    }
    out[b * 64 + j] = v;
}

extern "C" void kernel_launch(void* const* d_in, const int* in_sizes, int n_in,
                              void* d_out, int out_size, void* d_ws, size_t ws_size,
                              hipStream_t stream) {
    const float* nf   = (const float*)d_in[0];
    const float* ef   = (const float*)d_in[1];
    const float* l0w  = (const float*)d_in[2];
    const float* l0b  = (const float*)d_in[3];
    const float* w1   = (const float*)d_in[4];
    const float* b1   = (const float*)d_in[5];
    const float* w2   = (const float*)d_in[6];
    const float* b2   = (const float*)d_in[7];
    const float* cb   = (const float*)d_in[8];
    const float* gwih = (const float*)d_in[9];
    const float* gwhh = (const float*)d_in[10];
    const float* gbih = (const float*)d_in[11];
    const float* gbhh = (const float*)d_in[12];
    const float* lwih = (const float*)d_in[13];
    const float* lwhh = (const float*)d_in[14];
    const float* lbih = (const float*)d_in[15];
    const float* lbhh = (const float*)d_in[16];
    const int*   eidx = (const int*)d_in[17];
    const int*   gidx = (const int*)d_in[18];
    const int* src = eidx;
    const int* dst = eidx + N_EDGES;
    float* out = (float*)d_out;
    float* h   = out + (size_t)N_GRAPHS * 64;   // node state lives in d_out tail

    char* ws = (char*)d_ws;
    size_t off = 0;
    auto alloc = [&](size_t bytes) -> void* {
        void* p = ws + off;
        off = (off + bytes + 255) & ~(size_t)255;
        return p;
    };
    float* sbuf  = (float*)alloc((size_t)N_NODES * DIM * 4);   // 12.8 MB
    float* cnt   = (float*)alloc((size_t)N_NODES * 4);
    float* evec  = (float*)alloc((size_t)N_NODES * 4);
    float* hs    = (float*)alloc((size_t)N_GRAPHS * DIM * 4);
    float* cs    = (float*)alloc((size_t)N_GRAPHS * DIM * 4);
    float* rnum  = (float*)alloc((size_t)N_GRAPHS * DIM * 4);
    float* denom = (float*)alloc((size_t)N_GRAPHS * 4);
    unsigned* emax = (unsigned*)alloc((size_t)N_GRAPHS * 4);
    _Float16* w2f  = (_Float16*)alloc((size_t)W2F_HALFS * 2);  // 272 KB
    size_t fixed = off;
    size_t avail = ws_size > fixed ? ws_size - fixed : 0;

    auto need = [&](int nc) -> size_t {
        int cbk = (MSG_BLOCKS + nc - 1) / nc;
        return (size_t)cbk * 16 * 4096;   // 16 tiles/block * 4 KB/tile
    };
    int nchunk = 1;
    while (nchunk < 64 && need(nchunk) > avail) nchunk <<= 1;
    int chunk_blocks = (MSG_BLOCKS + nchunk - 1) / nchunk;
    _Float16* hwf = (_Float16*)alloc(need(nchunk));

    // ---- prologue ----
    lin0_kernel<<<dim3((N_NODES + 31) / 32), dim3(256), 0, stream>>>(nf, l0w, l0b, h);
    prep_w2f_kernel<<<dim3((W2F_HALFS + 255) / 256), dim3(256), 0, stream>>>(w2, b2, w2f);
    hipMemsetAsync(cnt, 0, (size_t)N_NODES * 4, stream);
    cnt_kernel<<<dim3((N_EDGES + 255) / 256), dim3(256), 0, stream>>>(dst, cnt);
    if (nchunk == 1) {
        hw_kernel<<<dim3(MSG_BLOCKS * 8), dim3(256), 0, stream>>>(ef, w1, b1, hwf, 0);
    }

    // ---- 3 message-passing + GRU iterations ----
    for (int it = 0; it < 3; ++it) {
        hipMemsetAsync(sbuf, 0, (size_t)N_NODES * DIM * 4, stream);
        for (int cix = 0; cix < nchunk; ++cix) {
            int bstart = cix * chunk_blocks;
            int bc = MSG_BLOCKS - bstart;
            if (bc <= 0) break;
            if (bc > chunk_blocks) bc = chunk_blocks;
            int e_off = bstart * 256;
            if (nchunk > 1)
                hw_kernel<<<dim3(bc * 8), dim3(256), 0, stream>>>(ef, w1, b1, hwf, e_off);
            msg_kernel<<<dim3(bc), dim3(256), 0, stream>>>(hwf, w2f, h, src, dst, sbuf, e_off);
        }
        gru_kernel<<<dim3((N_NODES + 63) / 64), dim3(256), 0, stream>>>(
            sbuf, cnt, cb, gwih, gwhh, gbih, gbhh, h);
    }

    // ---- Set2Set ----
    int s2s_blocks = (N_NODES + S2S_NB - 1) / S2S_NB;
    for (int st = 0; st < 3; ++st) {
        s2s_lstm_kernel<<<dim3((N_GRAPHS + 7) / 8), dim3(256), 0, stream>>>(
            lwih, lwhh, lbih, lbhh, hs, cs, rnum, denom, emax, st == 0 ? 1 : 0);
        s2s_dot_kernel<<<dim3(s2s_blocks), dim3(256), 0, stream>>>(
            h, hs, gidx, evec, emax);
        s2s_soft_kernel<<<dim3(s2s_blocks), dim3(256), 0, stream>>>(
            h, gidx, evec, emax, rnum, denom);
    }
    pooled_kernel<<<dim3((N_GRAPHS * 64 + 255) / 256), dim3(256), 0, stream>>>(
        hs, rnum, denom, out);
}

// Round 5
// 638.620 us; speedup vs baseline: 3.3135x; 1.3825x over previous
//
#include <hip/hip_runtime.h>
#include <stdint.h>

#define N_NODES  100000
#define N_EDGES  250000
#define N_GRAPHS 2000
#define F_IN     75
#define DIM      32
#define H1       128

#define MSG_BLOCKS 977           // ceil(250000/256), 256 edges per msg block
#define CH        8              // kt per LDS stage (16 KB)
#define NSTAGES   17
#define KT_PAD    (CH * NSTAGES) // 136, padded with zeros
#define W2F_HALFS (KT_PAD * 1024)

typedef _Float16 v8h __attribute__((ext_vector_type(8)));
typedef float    v4f __attribute__((ext_vector_type(4)));

__device__ __forceinline__ void gld_lds16(const void* g, void* l) {
    __builtin_amdgcn_global_load_lds(
        (const __attribute__((address_space(1))) unsigned int*)g,
        (__attribute__((address_space(3))) unsigned int*)l, 16, 0, 0);
}

// -------- lin0: h = relu(nf @ W.T + b), 32 nodes/block --------
__global__ __launch_bounds__(256) void lin0_kernel(
    const float* __restrict__ nf, const float* __restrict__ w,
    const float* __restrict__ b, float* __restrict__ h) {
    __shared__ float wl[DIM * F_IN];
    __shared__ float bl[DIM];
    int t = threadIdx.x;
    for (int i = t; i < DIM * F_IN; i += 256) wl[i] = w[i];
    if (t < DIM) bl[t] = b[t];
    __syncthreads();
    int nl = t >> 5, o = t & 31;
    #pragma unroll
    for (int p = 0; p < 4; ++p) {
        int n = blockIdx.x * 32 + p * 8 + nl;
        if (n >= N_NODES) continue;
        const float* row = nf + (size_t)n * F_IN;
        float acc = bl[o];
        #pragma unroll
        for (int i = 0; i < F_IN; ++i) acc += row[i] * wl[o * F_IN + i];
        h[n * DIM + o] = fmaxf(acc, 0.f);
    }
}

// -------- build W2t fragment-major fp16 table (+ b2 as kt=128, zeros beyond) --------
__global__ __launch_bounds__(256) void prep_w2f_kernel(
    const float* __restrict__ w2, const float* __restrict__ b2,
    _Float16* __restrict__ w2f) {
    int id = blockIdx.x * 256 + threadIdx.x;
    if (id >= W2F_HALFS) return;
    int j    = id & 7;
    int lane = (id >> 3) & 63;
    int ng   = (id >> 9) & 1;
    int kt   = id >> 10;
    int lr = lane & 15, q = lane >> 4;
    int c = kt * 32 + q * 8 + j;
    int o = ng * 16 + lr;
    float val = 0.f;
    if (c < 4096)      val = w2[((c >> 7) * 32 + o) * H1 + (c & 127)];
    else if (c < 4128) val = b2[(c - 4096) * 32 + o];
    w2f[id] = (_Float16)val;
}

// -------- edge hidden hw = relu(ef @ W1.T + b1), fp16 FRAG-MAJOR, 32 edges/block --------
__global__ __launch_bounds__(256) void hw_kernel(
    const float* __restrict__ ef, const float* __restrict__ w1,
    const float* __restrict__ b1, _Float16* __restrict__ hwf,
    int e_off) {
    __shared__ float wl[H1 * 11];
    __shared__ float bl[H1];
    int t = threadIdx.x;
    for (int i = t; i < H1 * 11; i += 256) wl[i] = w1[i];
    if (t < H1) bl[t] = b1[t];
    __syncthreads();
    int k = t & 127;
    #pragma unroll
    for (int p = 0; p < 16; ++p) {
        int le = blockIdx.x * 32 + p * 2 + (t >> 7);
        int e  = e_off + le;
        float acc = 0.f;
        if (e < N_EDGES) {
            const float* row = ef + (size_t)e * 11;
            acc = bl[k];
            #pragma unroll
            for (int i = 0; i < 11; ++i) acc += row[i] * wl[k * 11 + i];
            acc = fmaxf(acc, 0.f);
        }
        size_t addr = (size_t)(le >> 4) * 2048 + (k >> 3) * 128 + (le & 15) * 8 + (k & 7);
        hwf[addr] = (_Float16)acc;
    }
}

// -------- in-degree counts --------
__global__ __launch_bounds__(256) void cnt_kernel(
    const int* __restrict__ dst, float* __restrict__ cnt) {
    int e = blockIdx.x * 256 + threadIdx.x;
    if (e < N_EDGES) atomicAdd(&cnt[dst[e]], 1.0f);
}

// -------- per-graph node offsets (gidx sorted): gstart[b] = first n with gidx[n] >= b --------
__global__ __launch_bounds__(256) void offs_kernel(
    const int* __restrict__ gidx, int* __restrict__ gstart) {
    int n = blockIdx.x * 256 + threadIdx.x;
    if (n >= N_NODES) return;
    int b = gidx[n];
    if (n == 0) {
        for (int bb = 0; bb <= b; ++bb) gstart[bb] = 0;
    } else {
        int a = gidx[n - 1];
        for (int bb = a + 1; bb <= b; ++bb) gstart[bb] = n;
    }
    if (n == N_NODES - 1) {
        for (int bb = b + 1; bb <= N_GRAPHS; ++bb) gstart[bb] = N_NODES;
    }
}

// -------- fused message GEMM: msg = (x[src] (x) hw) @ W2t, LDS-staged B --------
__global__ __launch_bounds__(256) void msg_kernel(
    const _Float16* __restrict__ hwf, const _Float16* __restrict__ w2f,
    const float* __restrict__ x, const int* __restrict__ src,
    const int* __restrict__ dst, float* __restrict__ sbuf, int e_off) {
    __shared__ _Float16 xs[32 * 256];        // 16 KB: xs[i][e_loc]
    __shared__ _Float16 bst[2][CH * 1024];   // 2 x 16 KB B stages

    int t = threadIdx.x;
    int w = t >> 6, lane = t & 63, lr = lane & 15, q = lane >> 4;
    int wbase = w * 64;

    {
        const char* gp = (const char*)w2f;
        char* lp = (char*)&bst[0][0];
        #pragma unroll
        for (int it = 0; it < 4; ++it)
            gld_lds16(gp + it * 4096 + t * 16, lp + it * 4096 + t * 16);
    }

    v8h hwr[4][4];
    {
        const v8h* hv = (const v8h*)hwf;
        int T0 = blockIdx.x * 16 + w * 4;
        #pragma unroll
        for (int mt = 0; mt < 4; ++mt)
            #pragma unroll
            for (int kc = 0; kc < 4; ++kc)
                hwr[mt][kc] = hv[(size_t)(T0 + mt) * 256 + (kc * 4 + q) * 16 + lr];
    }

    {
        int e = e_off + blockIdx.x * 256 + t;
        int ec = e < N_EDGES ? e : N_EDGES - 1;
        int sv = src[ec];
        const float4* xr = (const float4*)(x + (size_t)sv * DIM);
        #pragma unroll
        for (int u = 0; u < 8; ++u) {
            float4 v = xr[u];
            xs[(u * 4 + 0) * 256 + t] = (_Float16)v.x;
            xs[(u * 4 + 1) * 256 + t] = (_Float16)v.y;
            xs[(u * 4 + 2) * 256 + t] = (_Float16)v.z;
            xs[(u * 4 + 3) * 256 + t] = (_Float16)v.w;
        }
    }
    __syncthreads();

    v4f acc[4][2];
    #pragma unroll
    for (int mt = 0; mt < 4; ++mt)
        #pragma unroll
        for (int ng = 0; ng < 2; ++ng) { v4f z = {0.f, 0.f, 0.f, 0.f}; acc[mt][ng] = z; }

    _Float16 xsc[4];

    for (int s = 0; s < NSTAGES - 1; ++s) {
        {
            const char* gp = (const char*)(w2f + (size_t)(s + 1) * CH * 1024);
            char* lp = (char*)&bst[(s + 1) & 1][0];
            #pragma unroll
            for (int it = 0; it < 4; ++it)
                gld_lds16(gp + it * 4096 + t * 16, lp + it * 4096 + t * 16);
        }
        const _Float16* bb = &bst[s & 1][0];
        #pragma unroll
        for (int ktl = 0; ktl < CH; ++ktl) {
            int kt = s * CH + ktl;
            v8h b0 = *(const v8h*)(bb + ktl * 1024 + lane * 8);
            v8h b1 = *(const v8h*)(bb + ktl * 1024 + 512 + lane * 8);
            if ((kt & 3) == 0) {
                int i = kt >> 2;
                #pragma unroll
                for (int mt = 0; mt < 4; ++mt)
                    xsc[mt] = xs[i * 256 + wbase + mt * 16 + lr];
            }
            int kc = kt & 3;
            #pragma unroll
            for (int mt = 0; mt < 4; ++mt) {
                v8h a = hwr[mt][kc] * xsc[mt];
                acc[mt][0] = __builtin_amdgcn_mfma_f32_16x16x32_f16(a, b0, acc[mt][0], 0, 0, 0);
                acc[mt][1] = __builtin_amdgcn_mfma_f32_16x16x32_f16(a, b1, acc[mt][1], 0, 0, 0);
            }
        }
        __syncthreads();
    }
    {
        const _Float16* bb = &bst[0][0];
        v8h b0 = *(const v8h*)(bb + lane * 8);
        v8h b1 = *(const v8h*)(bb + 512 + lane * 8);
        #pragma unroll
        for (int mt = 0; mt < 4; ++mt) {
            v8h a;
            #pragma unroll
            for (int j = 0; j < 8; ++j)
                a[j] = xs[(q * 8 + j) * 256 + wbase + mt * 16 + lr];
            acc[mt][0] = __builtin_amdgcn_mfma_f32_16x16x32_f16(a, b0, acc[mt][0], 0, 0, 0);
            acc[mt][1] = __builtin_amdgcn_mfma_f32_16x16x32_f16(a, b1, acc[mt][1], 0, 0, 0);
        }
    }

    int E0 = e_off + blockIdx.x * 256 + wbase;
    #pragma unroll
    for (int mt = 0; mt < 4; ++mt) {
        #pragma unroll
        for (int r = 0; r < 4; ++r) {
            int e = E0 + mt * 16 + q * 4 + r;
            if (e < N_EDGES) {
                int dv = dst[e];
                float* sp = sbuf + (size_t)dv * DIM;
                atomicAdd(sp + lr,      acc[mt][0][r]);
                atomicAdd(sp + 16 + lr, acc[mt][1][r]);
            }
        }
    }
}

// -------- MFMA GRU: scatter-mean finalize + conv_bias + relu + GRU cell --------
__global__ __launch_bounds__(256) void gru_kernel(
    const float* __restrict__ s, const float* __restrict__ cnt,
    const float* __restrict__ cb,
    const float* __restrict__ wih, const float* __restrict__ whh,
    const float* __restrict__ bih, const float* __restrict__ bhh,
    float* __restrict__ h) {
    __shared__ _Float16 m_l[64 * 32];   // 4 KB
    __shared__ _Float16 h_l[64 * 32];   // 4 KB
    int t = threadIdx.x;

    {
        int node_l = t >> 2, part = t & 3;
        int n = blockIdx.x * 64 + node_l;
        int nc = n < N_NODES ? n : N_NODES - 1;
        float c = cnt[nc];
        float rc = 1.f / (c > 1.f ? c : 1.f);
        const float4* s4 = (const float4*)(s + (size_t)nc * DIM + part * 8);
        float4 sa = s4[0], sb = s4[1];
        const float* cbp = cb + part * 8;
        v8h mv;
        mv[0] = (_Float16)fmaxf(sa.x * rc + cbp[0], 0.f);
        mv[1] = (_Float16)fmaxf(sa.y * rc + cbp[1], 0.f);
        mv[2] = (_Float16)fmaxf(sa.z * rc + cbp[2], 0.f);
        mv[3] = (_Float16)fmaxf(sa.w * rc + cbp[3], 0.f);
        mv[4] = (_Float16)fmaxf(sb.x * rc + cbp[4], 0.f);
        mv[5] = (_Float16)fmaxf(sb.y * rc + cbp[5], 0.f);
        mv[6] = (_Float16)fmaxf(sb.z * rc + cbp[6], 0.f);
        mv[7] = (_Float16)fmaxf(sb.w * rc + cbp[7], 0.f);
        *(v8h*)&m_l[node_l * 32 + part * 8] = mv;
        const float4* h4 = (const float4*)(h + (size_t)nc * DIM + part * 8);
        float4 ha = h4[0], hb = h4[1];
        v8h hv;
        hv[0] = (_Float16)ha.x; hv[1] = (_Float16)ha.y;
        hv[2] = (_Float16)ha.z; hv[3] = (_Float16)ha.w;
        hv[4] = (_Float16)hb.x; hv[5] = (_Float16)hb.y;
        hv[6] = (_Float16)hb.z; hv[7] = (_Float16)hb.w;
        *(v8h*)&h_l[node_l * 32 + part * 8] = hv;
    }

    int w = t >> 6, lane = t & 63, lr = lane & 15, q = lane >> 4;

    v8h bi6[6], bh6[6];
    v4f ai[6], ah[6];
    #pragma unroll
    for (int nt = 0; nt < 6; ++nt) {
        const float* wr = wih + (size_t)(nt * 16 + lr) * 32 + q * 8;
        float4 wa = *(const float4*)wr, wb = *(const float4*)(wr + 4);
        v8h bv;
        bv[0] = (_Float16)wa.x; bv[1] = (_Float16)wa.y;
        bv[2] = (_Float16)wa.z; bv[3] = (_Float16)wa.w;
        bv[4] = (_Float16)wb.x; bv[5] = (_Float16)wb.y;
        bv[6] = (_Float16)wb.z; bv[7] = (_Float16)wb.w;
        bi6[nt] = bv;
        const float* wr2 = whh + (size_t)(nt * 16 + lr) * 32 + q * 8;
        float4 ha2 = *(const float4*)wr2, hb2 = *(const float4*)(wr2 + 4);
        v8h bv2;
        bv2[0] = (_Float16)ha2.x; bv2[1] = (_Float16)ha2.y;
        bv2[2] = (_Float16)ha2.z; bv2[3] = (_Float16)ha2.w;
        bv2[4] = (_Float16)hb2.x; bv2[5] = (_Float16)hb2.y;
        bv2[6] = (_Float16)hb2.z; bv2[7] = (_Float16)hb2.w;
        bh6[nt] = bv2;
        float bii = bih[nt * 16 + lr], bhi = bhh[nt * 16 + lr];
        v4f ci = {bii, bii, bii, bii}; ai[nt] = ci;
        v4f chh = {bhi, bhi, bhi, bhi}; ah[nt] = chh;
    }

    __syncthreads();

    v8h ma = *(const v8h*)&m_l[(w * 16 + lr) * 32 + q * 8];
    v8h ha = *(const v8h*)&h_l[(w * 16 + lr) * 32 + q * 8];
    #pragma unroll
    for (int nt = 0; nt < 6; ++nt) {
        ai[nt] = __builtin_amdgcn_mfma_f32_16x16x32_f16(ma, bi6[nt], ai[nt], 0, 0, 0);
        ah[nt] = __builtin_amdgcn_mfma_f32_16x16x32_f16(ha, bh6[nt], ah[nt], 0, 0, 0);
    }

    int nb = blockIdx.x * 64 + w * 16 + q * 4;
    #pragma unroll
    for (int g = 0; g < 2; ++g) {
        int o = g * 16 + lr;
        #pragma unroll
        for (int r = 0; r < 4; ++r) {
            int n2 = nb + r;
            if (n2 < N_NODES) {
                float rg = 1.f / (1.f + expf(-(ai[g][r]     + ah[g][r])));
                float zg = 1.f / (1.f + expf(-(ai[2 + g][r] + ah[2 + g][r])));
                float ng = tanhf(ai[4 + g][r] + rg * ah[4 + g][r]);
                float hold = h[(size_t)n2 * DIM + o];
                h[(size_t)n2 * DIM + o] = (1.f - zg) * ng + zg * hold;
            }
        }
    }
}

// -------- Set2Set LSTM: q_star assembled inline from (h, rnum, denom) --------
__global__ __launch_bounds__(256) void s2s_lstm_kernel(
    const float* __restrict__ wih, const float* __restrict__ whh,
    const float* __restrict__ bih, const float* __restrict__ bhh,
    float* __restrict__ h, float* __restrict__ c,
    const float* __restrict__ rnum, const float* __restrict__ denom,
    int first) {
    __shared__ float wA[128 * 33], wB[128 * 33], bl[128];
    int t = threadIdx.x;
    for (int i = t; i < 128 * 32; i += 256) {
        int r = i >> 5, cc = i & 31;
        wA[r * 33 + cc] = wih[r * 64 + cc] + whh[r * 32 + cc];
        wB[r * 33 + cc] = wih[r * 64 + 32 + cc];
    }
    if (t < 128) bl[t] = bih[t] + bhh[t];
    __syncthreads();
    int gl = t >> 5, o = t & 31;
    int b = blockIdx.x * 8 + gl;
    if (b >= N_GRAPHS) return;
    float hq = 0.f, rr = 0.f, cv = 0.f;
    if (!first) {
        hq = h[b * DIM + o];
        float d = denom[b];
        rr = d > 0.f ? rnum[b * DIM + o] / d : 0.f;
        cv = c[b * DIM + o];
    }
    float gi = bl[o], gf = bl[32 + o], gg = bl[64 + o], go = bl[96 + o];
    #pragma unroll
    for (int i = 0; i < 32; ++i) {
        float qv = __shfl(hq, i, 32);
        float rv = __shfl(rr, i, 32);
        gi += qv * wA[o * 33 + i]        + rv * wB[o * 33 + i];
        gf += qv * wA[(32 + o) * 33 + i] + rv * wB[(32 + o) * 33 + i];
        gg += qv * wA[(64 + o) * 33 + i] + rv * wB[(64 + o) * 33 + i];
        go += qv * wA[(96 + o) * 33 + i] + rv * wB[(96 + o) * 33 + i];
    }
    float si = 1.f / (1.f + expf(-gi));
    float sf = 1.f / (1.f + expf(-gf));
    float so = 1.f / (1.f + expf(-go));
    float cn = sf * cv + si * tanhf(gg);
    c[b * DIM + o] = cn;
    h[b * DIM + o] = so * tanhf(cn);
}

// -------- fused Set2Set attention: one 32-lane group per graph, online softmax --------
// reads h once; no atomics; writes rnum[b,:]=sum(a*x), denom[b]=sum(exp)
__global__ __launch_bounds__(256) void s2s_attn_kernel(
    const float* __restrict__ x, const float* __restrict__ q,
    const int* __restrict__ gstart,
    float* __restrict__ rnum, float* __restrict__ denom) {
    int t = threadIdx.x;
    int g = t >> 5, o = t & 31;
    int b = blockIdx.x * 8 + g;
    if (b >= N_GRAPHS) return;
    int n0 = gstart[b], n1 = gstart[b + 1];
    float qo = q[b * DIM + o];
    float m0 = -3.0e38f, s = 0.f, r = 0.f;
    for (int n = n0; n < n1; ++n) {
        float xo = x[(size_t)n * DIM + o];
        float e = xo * qo;
        #pragma unroll
        for (int mm = 16; mm >= 1; mm >>= 1) e += __shfl_xor(e, mm, 32);
        float nm = fmaxf(m0, e);
        float sc = expf(m0 - nm);
        float ex = expf(e - nm);
        s = s * sc + ex;
        r = r * sc + ex * xo;
        m0 = nm;
    }
    rnum[b * DIM + o] = r;
    if (o == 0) denom[b] = s;
}

// -------- final pooled output: out[b] = [q, rnum/denom] --------
__global__ __launch_bounds__(256) void pooled_kernel(
    const float* __restrict__ h, const float* __restrict__ rnum,
    const float* __restrict__ denom, float* __restrict__ out) {
    int t = blockIdx.x * 256 + threadIdx.x;
    int b = t >> 6, j = t & 63;
    if (b >= N_GRAPHS) return;
    float v;
    if (j < 32) v = h[b * DIM + j];
    else {
        float d = denom[b];
        v = d > 0.f ? rnum[b * DIM + (j - 32)] / d : 0.f;
    }
    out[b * 64 + j] = v;
}

extern "C" void kernel_launch(void* const* d_in, const int* in_sizes, int n_in,
                              void* d_out, int out_size, void* d_ws, size_t ws_size,
                              hipStream_t stream) {
    const float* nf   = (const float*)d_in[0];
    const float* ef   = (const float*)d_in[1];
    const float* l0w  = (const float*)d_in[2];
    const float* l0b  = (const float*)d_in[3];
    const float* w1   = (const float*)d_in[4];
    const float* b1   = (const float*)d_in[5];
    const float* w2   = (const float*)d_in[6];
    const float* b2   = (const float*)d_in[7];
    const float* cb   = (const float*)d_in[8];
    const float* gwih = (const float*)d_in[9];
    const float* gwhh = (const float*)d_in[10];
    const float* gbih = (const float*)d_in[11];
    const float* gbhh = (const float*)d_in[12];
    const float* lwih = (const float*)d_in[13];
    const float* lwhh = (const float*)d_in[14];
    const float* lbih = (const float*)d_in[15];
    const float* lbhh = (const float*)d_in[16];
    const int*   eidx = (const int*)d_in[17];
    const int*   gidx = (const int*)d_in[18];
    const int* src = eidx;
    const int* dst = eidx + N_EDGES;
    float* out = (float*)d_out;
    float* h   = out + (size_t)N_GRAPHS * 64;   // node state lives in d_out tail

    char* ws = (char*)d_ws;
    size_t off = 0;
    auto alloc = [&](size_t bytes) -> void* {
        void* p = ws + off;
        off = (off + bytes + 255) & ~(size_t)255;
        return p;
    };
    float* sbuf  = (float*)alloc((size_t)N_NODES * DIM * 4);   // 12.8 MB
    float* cnt   = (float*)alloc((size_t)N_NODES * 4);
    float* hs    = (float*)alloc((size_t)N_GRAPHS * DIM * 4);
    float* cs    = (float*)alloc((size_t)N_GRAPHS * DIM * 4);
    float* rnum  = (float*)alloc((size_t)N_GRAPHS * DIM * 4);
    float* denom = (float*)alloc((size_t)N_GRAPHS * 4);
    int*   gstart = (int*)alloc((size_t)(N_GRAPHS + 1) * 4);
    _Float16* w2f  = (_Float16*)alloc((size_t)W2F_HALFS * 2);  // 272 KB
    size_t fixed = off;
    size_t avail = ws_size > fixed ? ws_size - fixed : 0;

    auto need = [&](int nc) -> size_t {
        int cbk = (MSG_BLOCKS + nc - 1) / nc;
        return (size_t)cbk * 16 * 4096;   // 16 tiles/block * 4 KB/tile
    };
    int nchunk = 1;
    while (nchunk < 64 && need(nchunk) > avail) nchunk <<= 1;
    int chunk_blocks = (MSG_BLOCKS + nchunk - 1) / nchunk;
    _Float16* hwf = (_Float16*)alloc(need(nchunk));

    // ---- prologue ----
    lin0_kernel<<<dim3((N_NODES + 31) / 32), dim3(256), 0, stream>>>(nf, l0w, l0b, h);
    prep_w2f_kernel<<<dim3((W2F_HALFS + 255) / 256), dim3(256), 0, stream>>>(w2, b2, w2f);
    hipMemsetAsync(cnt, 0, (size_t)N_NODES * 4, stream);
    cnt_kernel<<<dim3((N_EDGES + 255) / 256), dim3(256), 0, stream>>>(dst, cnt);
    offs_kernel<<<dim3((N_NODES + 255) / 256), dim3(256), 0, stream>>>(gidx, gstart);
    if (nchunk == 1) {
        hw_kernel<<<dim3(MSG_BLOCKS * 8), dim3(256), 0, stream>>>(ef, w1, b1, hwf, 0);
    }

    // ---- 3 message-passing + GRU iterations ----
    for (int it = 0; it < 3; ++it) {
        hipMemsetAsync(sbuf, 0, (size_t)N_NODES * DIM * 4, stream);
        for (int cix = 0; cix < nchunk; ++cix) {
            int bstart = cix * chunk_blocks;
            int bc = MSG_BLOCKS - bstart;
            if (bc <= 0) break;
            if (bc > chunk_blocks) bc = chunk_blocks;
            int e_off = bstart * 256;
            if (nchunk > 1)
                hw_kernel<<<dim3(bc * 8), dim3(256), 0, stream>>>(ef, w1, b1, hwf, e_off);
            msg_kernel<<<dim3(bc), dim3(256), 0, stream>>>(hwf, w2f, h, src, dst, sbuf, e_off);
        }
        gru_kernel<<<dim3((N_NODES + 63) / 64), dim3(256), 0, stream>>>(
            sbuf, cnt, cb, gwih, gwhh, gbih, gbhh, h);
    }

    // ---- Set2Set ----
    for (int st = 0; st < 3; ++st) {
        s2s_lstm_kernel<<<dim3((N_GRAPHS + 7) / 8), dim3(256), 0, stream>>>(
            lwih, lwhh, lbih, lbhh, hs, cs, rnum, denom, st == 0 ? 1 : 0);
        s2s_attn_kernel<<<dim3((N_GRAPHS + 7) / 8), dim3(256), 0, stream>>>(
            h, hs, gstart, rnum, denom);
    }
    pooled_kernel<<<dim3((N_GRAPHS * 64 + 255) / 256), dim3(256), 0, stream>>>(
        hs, rnum, denom, out);
}

// Round 6
// 622.176 us; speedup vs baseline: 3.4011x; 1.0264x over previous
//
#include <hip/hip_runtime.h>
#include <stdint.h>

#define N_NODES  100000
#define N_EDGES  250000
#define N_GRAPHS 2000
#define F_IN     75
#define DIM      32
#define H1       128

#define MSG_BLOCKS 977           // ceil(250000/256), 256 edges per msg block
#define CH        4              // kt per LDS stage (8 KB)
#define NSTAGES   33             // stages 0..32; stage 32 = bias kt=128 (+3 zero kt)
#define KT_PAD    (CH * NSTAGES) // 132
#define W2F_HALFS (KT_PAD * 1024)

typedef _Float16 v8h __attribute__((ext_vector_type(8)));
typedef float    v4f __attribute__((ext_vector_type(4)));

__device__ __forceinline__ void gld_lds16(const void* g, void* l) {
    __builtin_amdgcn_global_load_lds(
        (const __attribute__((address_space(1))) unsigned int*)g,
        (__attribute__((address_space(3))) unsigned int*)l, 16, 0, 0);
}

// -------- lin0: h = relu(nf @ W.T + b), 32 nodes/block --------
__global__ __launch_bounds__(256) void lin0_kernel(
    const float* __restrict__ nf, const float* __restrict__ w,
    const float* __restrict__ b, float* __restrict__ h) {
    __shared__ float wl[DIM * F_IN];
    __shared__ float bl[DIM];
    int t = threadIdx.x;
    for (int i = t; i < DIM * F_IN; i += 256) wl[i] = w[i];
    if (t < DIM) bl[t] = b[t];
    __syncthreads();
    int nl = t >> 5, o = t & 31;
    #pragma unroll
    for (int p = 0; p < 4; ++p) {
        int n = blockIdx.x * 32 + p * 8 + nl;
        if (n >= N_NODES) continue;
        const float* row = nf + (size_t)n * F_IN;
        float acc = bl[o];
        #pragma unroll
        for (int i = 0; i < F_IN; ++i) acc += row[i] * wl[o * F_IN + i];
        h[n * DIM + o] = fmaxf(acc, 0.f);
    }
}

// -------- build W2t fragment-major fp16 table (+ b2 as kt=128, zeros beyond) --------
__global__ __launch_bounds__(256) void prep_w2f_kernel(
    const float* __restrict__ w2, const float* __restrict__ b2,
    _Float16* __restrict__ w2f) {
    int id = blockIdx.x * 256 + threadIdx.x;
    if (id >= W2F_HALFS) return;
    int j    = id & 7;
    int lane = (id >> 3) & 63;
    int ng   = (id >> 9) & 1;
    int kt   = id >> 10;
    int lr = lane & 15, q = lane >> 4;
    int c = kt * 32 + q * 8 + j;
    int o = ng * 16 + lr;
    float val = 0.f;
    if (c < 4096)      val = w2[((c >> 7) * 32 + o) * H1 + (c & 127)];
    else if (c < 4128) val = b2[(c - 4096) * 32 + o];
    w2f[id] = (_Float16)val;
}

// -------- edge hidden hw = relu(ef @ W1.T + b1), fp16 FRAG-MAJOR, 32 edges/block --------
__global__ __launch_bounds__(256) void hw_kernel(
    const float* __restrict__ ef, const float* __restrict__ w1,
    const float* __restrict__ b1, _Float16* __restrict__ hwf,
    int e_off) {
    __shared__ float wl[H1 * 11];
    __shared__ float bl[H1];
    int t = threadIdx.x;
    for (int i = t; i < H1 * 11; i += 256) wl[i] = w1[i];
    if (t < H1) bl[t] = b1[t];
    __syncthreads();
    int k = t & 127;
    #pragma unroll
    for (int p = 0; p < 16; ++p) {
        int le = blockIdx.x * 32 + p * 2 + (t >> 7);
        int e  = e_off + le;
        float acc = 0.f;
        if (e < N_EDGES) {
            const float* row = ef + (size_t)e * 11;
            acc = bl[k];
            #pragma unroll
            for (int i = 0; i < 11; ++i) acc += row[i] * wl[k * 11 + i];
            acc = fmaxf(acc, 0.f);
        }
        size_t addr = (size_t)(le >> 4) * 2048 + (k >> 3) * 128 + (le & 15) * 8 + (k & 7);
        hwf[addr] = (_Float16)acc;
    }
}

// -------- in-degree counts --------
__global__ __launch_bounds__(256) void cnt_kernel(
    const int* __restrict__ dst, float* __restrict__ cnt) {
    int e = blockIdx.x * 256 + threadIdx.x;
    if (e < N_EDGES) atomicAdd(&cnt[dst[e]], 1.0f);
}

// -------- per-graph node offsets (gidx sorted) --------
__global__ __launch_bounds__(256) void offs_kernel(
    const int* __restrict__ gidx, int* __restrict__ gstart) {
    int n = blockIdx.x * 256 + threadIdx.x;
    if (n >= N_NODES) return;
    int b = gidx[n];
    if (n == 0) {
        for (int bb = 0; bb <= b; ++bb) gstart[bb] = 0;
    } else {
        int a = gidx[n - 1];
        for (int bb = a + 1; bb <= b; ++bb) gstart[bb] = n;
    }
    if (n == N_NODES - 1) {
        for (int bb = b + 1; bb <= N_GRAPHS; ++bb) gstart[bb] = N_NODES;
    }
}

// -------- fused message GEMM: msg = (x[src] (x) hw) @ W2t, LDS-staged B --------
// 256 threads = 4 waves, 256 edges/block; LDS 32 KB -> 5 blocks/CU
__global__ __launch_bounds__(256) void msg_kernel(
    const _Float16* __restrict__ hwf, const _Float16* __restrict__ w2f,
    const float* __restrict__ x, const int* __restrict__ src,
    const int* __restrict__ dst, float* __restrict__ sbuf, int e_off) {
    __shared__ _Float16 xs[32 * 256];        // 16 KB: xs[i][e_loc]
    __shared__ _Float16 bst[2][CH * 1024];   // 2 x 8 KB B stages

    int t = threadIdx.x;
    int w = t >> 6, lane = t & 63, lr = lane & 15, q = lane >> 4;
    int wbase = w * 64;

    // stage-0 B prefetch (8 KB)
    {
        const char* gp = (const char*)w2f;
        char* lp = (char*)&bst[0][0];
        gld_lds16(gp + t * 16, lp + t * 16);
        gld_lds16(gp + 4096 + t * 16, lp + 4096 + t * 16);
    }

    // preload hw fragments for this wave's 64 edges
    v8h hwr[4][4];
    {
        const v8h* hv = (const v8h*)hwf;
        int T0 = blockIdx.x * 16 + w * 4;
        #pragma unroll
        for (int mt = 0; mt < 4; ++mt)
            #pragma unroll
            for (int kc = 0; kc < 4; ++kc)
                hwr[mt][kc] = hv[(size_t)(T0 + mt) * 256 + (kc * 4 + q) * 16 + lr];
    }

    // stage x[src] (fp32 -> fp16)
    {
        int e = e_off + blockIdx.x * 256 + t;
        int ec = e < N_EDGES ? e : N_EDGES - 1;
        int sv = src[ec];
        const float4* xr = (const float4*)(x + (size_t)sv * DIM);
        #pragma unroll
        for (int u = 0; u < 8; ++u) {
            float4 v = xr[u];
            xs[(u * 4 + 0) * 256 + t] = (_Float16)v.x;
            xs[(u * 4 + 1) * 256 + t] = (_Float16)v.y;
            xs[(u * 4 + 2) * 256 + t] = (_Float16)v.z;
            xs[(u * 4 + 3) * 256 + t] = (_Float16)v.w;
        }
    }
    __syncthreads();

    v4f acc[4][2];
    #pragma unroll
    for (int mt = 0; mt < 4; ++mt)
        #pragma unroll
        for (int ng = 0; ng < 2; ++ng) { v4f z = {0.f, 0.f, 0.f, 0.f}; acc[mt][ng] = z; }

    for (int s = 0; s < 32; ++s) {
        // prefetch stage s+1 (<= 32) into other buffer
        {
            const char* gp = (const char*)(w2f + (size_t)(s + 1) * CH * 1024);
            char* lp = (char*)&bst[(s + 1) & 1][0];
            gld_lds16(gp + t * 16, lp + t * 16);
            gld_lds16(gp + 4096 + t * 16, lp + 4096 + t * 16);
        }
        // x scalars for this i-group (i == s)
        _Float16 xsc[4];
        #pragma unroll
        for (int mt = 0; mt < 4; ++mt)
            xsc[mt] = xs[s * 256 + wbase + mt * 16 + lr];
        const _Float16* bb = &bst[s & 1][0];
        #pragma unroll
        for (int ktl = 0; ktl < CH; ++ktl) {
            v8h b0 = *(const v8h*)(bb + ktl * 1024 + lane * 8);
            v8h b1 = *(const v8h*)(bb + ktl * 1024 + 512 + lane * 8);
            #pragma unroll
            for (int mt = 0; mt < 4; ++mt) {
                v8h a = hwr[mt][ktl] * xsc[mt];
                acc[mt][0] = __builtin_amdgcn_mfma_f32_16x16x32_f16(a, b0, acc[mt][0], 0, 0, 0);
                acc[mt][1] = __builtin_amdgcn_mfma_f32_16x16x32_f16(a, b1, acc[mt][1], 0, 0, 0);
            }
        }
        __syncthreads();
    }
    // bias step: stage 32 sits in bst[0], kt=128 at its head; A = x[src] direct
    {
        const _Float16* bb = &bst[0][0];
        v8h b0 = *(const v8h*)(bb + lane * 8);
        v8h b1 = *(const v8h*)(bb + 512 + lane * 8);
        #pragma unroll
        for (int mt = 0; mt < 4; ++mt) {
            v8h a;
            #pragma unroll
            for (int j = 0; j < 8; ++j)
                a[j] = xs[(q * 8 + j) * 256 + wbase + mt * 16 + lr];
            acc[mt][0] = __builtin_amdgcn_mfma_f32_16x16x32_f16(a, b0, acc[mt][0], 0, 0, 0);
            acc[mt][1] = __builtin_amdgcn_mfma_f32_16x16x32_f16(a, b1, acc[mt][1], 0, 0, 0);
        }
    }

    // epilogue: D[m = q*4+r][n = lr]; scatter-add to sbuf[dst]
    int E0 = e_off + blockIdx.x * 256 + wbase;
    #pragma unroll
    for (int mt = 0; mt < 4; ++mt) {
        #pragma unroll
        for (int r = 0; r < 4; ++r) {
            int e = E0 + mt * 16 + q * 4 + r;
            if (e < N_EDGES) {
                int dv = dst[e];
                float* sp = sbuf + (size_t)dv * DIM;
                atomicAdd(sp + lr,      acc[mt][0][r]);
                atomicAdd(sp + 16 + lr, acc[mt][1][r]);
            }
        }
    }
}

// -------- MFMA GRU: scatter-mean finalize + conv_bias + relu + GRU; zeroes sbuf --------
__global__ __launch_bounds__(256) void gru_kernel(
    float* __restrict__ s, const float* __restrict__ cnt,
    const float* __restrict__ cb,
    const float* __restrict__ wih, const float* __restrict__ whh,
    const float* __restrict__ bih, const float* __restrict__ bhh,
    float* __restrict__ h) {
    __shared__ _Float16 wi_l[96 * 40], wh_l[96 * 40];  // stride 40: conflict-free frags
    __shared__ float bi_l[96], bh_l[96];
    __shared__ _Float16 m_l[64 * 32], h_l[64 * 32];
    int t = threadIdx.x;

    for (int i = t; i < 96 * 32; i += 256) {
        int r = i >> 5, c2 = i & 31;
        wi_l[r * 40 + c2] = (_Float16)wih[i];
        wh_l[r * 40 + c2] = (_Float16)whh[i];
    }
    if (t < 96) { bi_l[t] = bih[t]; bh_l[t] = bhh[t]; }

    // stage m = relu(s/cnt + cb) and h into LDS fp16; zero sbuf for next iteration
    {
        int node_l = t >> 2, part = t & 3;
        int n = blockIdx.x * 64 + node_l;
        int nc = n < N_NODES ? n : N_NODES - 1;
        float c = cnt[nc];
        float rc = 1.f / (c > 1.f ? c : 1.f);
        float4* s4 = (float4*)(s + (size_t)nc * DIM + part * 8);
        float4 sa = s4[0], sb = s4[1];
        const float* cbp = cb + part * 8;
        v8h mv;
        mv[0] = (_Float16)fmaxf(sa.x * rc + cbp[0], 0.f);
        mv[1] = (_Float16)fmaxf(sa.y * rc + cbp[1], 0.f);
        mv[2] = (_Float16)fmaxf(sa.z * rc + cbp[2], 0.f);
        mv[3] = (_Float16)fmaxf(sa.w * rc + cbp[3], 0.f);
        mv[4] = (_Float16)fmaxf(sb.x * rc + cbp[4], 0.f);
        mv[5] = (_Float16)fmaxf(sb.y * rc + cbp[5], 0.f);
        mv[6] = (_Float16)fmaxf(sb.z * rc + cbp[6], 0.f);
        mv[7] = (_Float16)fmaxf(sb.w * rc + cbp[7], 0.f);
        *(v8h*)&m_l[node_l * 32 + part * 8] = mv;
        if (n < N_NODES) {
            float4 z4 = {0.f, 0.f, 0.f, 0.f};
            s4[0] = z4; s4[1] = z4;
        }
        const float4* h4 = (const float4*)(h + (size_t)nc * DIM + part * 8);
        float4 ha = h4[0], hb = h4[1];
        v8h hv;
        hv[0] = (_Float16)ha.x; hv[1] = (_Float16)ha.y;
        hv[2] = (_Float16)ha.z; hv[3] = (_Float16)ha.w;
        hv[4] = (_Float16)hb.x; hv[5] = (_Float16)hb.y;
        hv[6] = (_Float16)hb.z; hv[7] = (_Float16)hb.w;
        *(v8h*)&h_l[node_l * 32 + part * 8] = hv;
    }

    __syncthreads();

    int w = t >> 6, lane = t & 63, lr = lane & 15, q = lane >> 4;

    v8h bi6[6], bh6[6];
    v4f ai[6], ah[6];
    #pragma unroll
    for (int nt = 0; nt < 6; ++nt) {
        bi6[nt] = *(const v8h*)&wi_l[(nt * 16 + lr) * 40 + q * 8];
        bh6[nt] = *(const v8h*)&wh_l[(nt * 16 + lr) * 40 + q * 8];
        float bii = bi_l[nt * 16 + lr], bhi = bh_l[nt * 16 + lr];
        v4f ci = {bii, bii, bii, bii}; ai[nt] = ci;
        v4f chh = {bhi, bhi, bhi, bhi}; ah[nt] = chh;
    }

    v8h ma = *(const v8h*)&m_l[(w * 16 + lr) * 32 + q * 8];
    v8h ha = *(const v8h*)&h_l[(w * 16 + lr) * 32 + q * 8];
    #pragma unroll
    for (int nt = 0; nt < 6; ++nt) {
        ai[nt] = __builtin_amdgcn_mfma_f32_16x16x32_f16(ma, bi6[nt], ai[nt], 0, 0, 0);
        ah[nt] = __builtin_amdgcn_mfma_f32_16x16x32_f16(ha, bh6[nt], ah[nt], 0, 0, 0);
    }

    int nb = blockIdx.x * 64 + w * 16 + q * 4;
    #pragma unroll
    for (int g = 0; g < 2; ++g) {
        int o = g * 16 + lr;
        #pragma unroll
        for (int r = 0; r < 4; ++r) {
            int n2 = nb + r;
            if (n2 < N_NODES) {
                float rg = 1.f / (1.f + expf(-(ai[g][r]     + ah[g][r])));
                float zg = 1.f / (1.f + expf(-(ai[2 + g][r] + ah[2 + g][r])));
                float ng = tanhf(ai[4 + g][r] + rg * ah[4 + g][r]);
                float hold = h[(size_t)n2 * DIM + o];
                h[(size_t)n2 * DIM + o] = (1.f - zg) * ng + zg * hold;
            }
        }
    }
}

// -------- Set2Set LSTM: q_star assembled inline from (h, rnum, denom) --------
__global__ __launch_bounds__(256) void s2s_lstm_kernel(
    const float* __restrict__ wih, const float* __restrict__ whh,
    const float* __restrict__ bih, const float* __restrict__ bhh,
    float* __restrict__ h, float* __restrict__ c,
    const float* __restrict__ rnum, const float* __restrict__ denom,
    int first) {
    __shared__ float wA[128 * 33], wB[128 * 33], bl[128];
    int t = threadIdx.x;
    for (int i = t; i < 128 * 32; i += 256) {
        int r = i >> 5, cc = i & 31;
        wA[r * 33 + cc] = wih[r * 64 + cc] + whh[r * 32 + cc];
        wB[r * 33 + cc] = wih[r * 64 + 32 + cc];
    }
    if (t < 128) bl[t] = bih[t] + bhh[t];
    __syncthreads();
    int gl = t >> 5, o = t & 31;
    int b = blockIdx.x * 8 + gl;
    if (b >= N_GRAPHS) return;
    float hq = 0.f, rr = 0.f, cv = 0.f;
    if (!first) {
        hq = h[b * DIM + o];
        float d = denom[b];
        rr = d > 0.f ? rnum[b * DIM + o] / d : 0.f;
        cv = c[b * DIM + o];
    }
    float gi = bl[o], gf = bl[32 + o], gg = bl[64 + o], go = bl[96 + o];
    #pragma unroll
    for (int i = 0; i < 32; ++i) {
        float qv = __shfl(hq, i, 32);
        float rv = __shfl(rr, i, 32);
        gi += qv * wA[o * 33 + i]        + rv * wB[o * 33 + i];
        gf += qv * wA[(32 + o) * 33 + i] + rv * wB[(32 + o) * 33 + i];
        gg += qv * wA[(64 + o) * 33 + i] + rv * wB[(64 + o) * 33 + i];
        go += qv * wA[(96 + o) * 33 + i] + rv * wB[(96 + o) * 33 + i];
    }
    float si = 1.f / (1.f + expf(-gi));
    float sf = 1.f / (1.f + expf(-gf));
    float so = 1.f / (1.f + expf(-go));
    float cn = sf * cv + si * tanhf(gg);
    c[b * DIM + o] = cn;
    h[b * DIM + o] = so * tanhf(cn);
}

// -------- fused Set2Set attention (online softmax); optionally writes final out --------
__global__ __launch_bounds__(256) void s2s_attn_kernel(
    const float* __restrict__ x, const float* __restrict__ q,
    const int* __restrict__ gstart,
    float* __restrict__ rnum, float* __restrict__ denom,
    float* __restrict__ outp, int wout) {
    int t = threadIdx.x;
    int g = t >> 5, o = t & 31;
    int b = blockIdx.x * 8 + g;
    if (b >= N_GRAPHS) return;
    int n0 = gstart[b], n1 = gstart[b + 1];
    float qo = q[b * DIM + o];
    float m0 = -3.0e38f, s = 0.f, r = 0.f;
    for (int n = n0; n < n1; ++n) {
        float xo = x[(size_t)n * DIM + o];
        float e = xo * qo;
        #pragma unroll
        for (int mm = 16; mm >= 1; mm >>= 1) e += __shfl_xor(e, mm, 32);
        float nm = fmaxf(m0, e);
        float sc = expf(m0 - nm);
        float ex = expf(e - nm);
        s = s * sc + ex;
        r = r * sc + ex * xo;
        m0 = nm;
    }
    rnum[b * DIM + o] = r;
    if (o == 0) denom[b] = s;
    if (wout) {
        outp[b * 64 + o]      = qo;
        outp[b * 64 + 32 + o] = s > 0.f ? r / s : 0.f;
    }
}

extern "C" void kernel_launch(void* const* d_in, const int* in_sizes, int n_in,
                              void* d_out, int out_size, void* d_ws, size_t ws_size,
                              hipStream_t stream) {
    const float* nf   = (const float*)d_in[0];
    const float* ef   = (const float*)d_in[1];
    const float* l0w  = (const float*)d_in[2];
    const float* l0b  = (const float*)d_in[3];
    const float* w1   = (const float*)d_in[4];
    const float* b1   = (const float*)d_in[5];
    const float* w2   = (const float*)d_in[6];
    const float* b2   = (const float*)d_in[7];
    const float* cb   = (const float*)d_in[8];
    const float* gwih = (const float*)d_in[9];
    const float* gwhh = (const float*)d_in[10];
    const float* gbih = (const float*)d_in[11];
    const float* gbhh = (const float*)d_in[12];
    const float* lwih = (const float*)d_in[13];
    const float* lwhh = (const float*)d_in[14];
    const float* lbih = (const float*)d_in[15];
    const float* lbhh = (const float*)d_in[16];
    const int*   eidx = (const int*)d_in[17];
    const int*   gidx = (const int*)d_in[18];
    const int* src = eidx;
    const int* dst = eidx + N_EDGES;
    float* out = (float*)d_out;
    float* h   = out + (size_t)N_GRAPHS * 64;   // node state lives in d_out tail

    char* ws = (char*)d_ws;
    size_t off = 0;
    auto alloc = [&](size_t bytes) -> void* {
        void* p = ws + off;
        off = (off + bytes + 255) & ~(size_t)255;
        return p;
    };
    float* sbuf  = (float*)alloc((size_t)N_NODES * DIM * 4);   // 12.8 MB
    float* cnt   = (float*)alloc((size_t)N_NODES * 4);
    float* hs    = (float*)alloc((size_t)N_GRAPHS * DIM * 4);
    float* cs    = (float*)alloc((size_t)N_GRAPHS * DIM * 4);
    float* rnum  = (float*)alloc((size_t)N_GRAPHS * DIM * 4);
    float* denom = (float*)alloc((size_t)N_GRAPHS * 4);
    int*   gstart = (int*)alloc((size_t)(N_GRAPHS + 1) * 4);
    _Float16* w2f  = (_Float16*)alloc((size_t)W2F_HALFS * 2);  // 264 KB
    size_t fixed = off;
    size_t avail = ws_size > fixed ? ws_size - fixed : 0;

    auto need = [&](int nc) -> size_t {
        int cbk = (MSG_BLOCKS + nc - 1) / nc;
        return (size_t)cbk * 16 * 4096;   // 16 tiles/block * 4 KB/tile
    };
    int nchunk = 1;
    while (nchunk < 64 && need(nchunk) > avail) nchunk <<= 1;
    int chunk_blocks = (MSG_BLOCKS + nchunk - 1) / nchunk;
    _Float16* hwf = (_Float16*)alloc(need(nchunk));

    // ---- prologue ----
    lin0_kernel<<<dim3((N_NODES + 31) / 32), dim3(256), 0, stream>>>(nf, l0w, l0b, h);
    prep_w2f_kernel<<<dim3((W2F_HALFS + 255) / 256), dim3(256), 0, stream>>>(w2, b2, w2f);
    hipMemsetAsync(cnt, 0, (size_t)N_NODES * 4, stream);
    cnt_kernel<<<dim3((N_EDGES + 255) / 256), dim3(256), 0, stream>>>(dst, cnt);
    offs_kernel<<<dim3((N_NODES + 255) / 256), dim3(256), 0, stream>>>(gidx, gstart);
    if (nchunk == 1) {
        hw_kernel<<<dim3(MSG_BLOCKS * 8), dim3(256), 0, stream>>>(ef, w1, b1, hwf, 0);
    }
    hipMemsetAsync(sbuf, 0, (size_t)N_NODES * DIM * 4, stream);  // once; gru re-zeroes

    // ---- 3 message-passing + GRU iterations ----
    for (int it = 0; it < 3; ++it) {
        for (int cix = 0; cix < nchunk; ++cix) {
            int bstart = cix * chunk_blocks;
            int bc = MSG_BLOCKS - bstart;
            if (bc <= 0) break;
            if (bc > chunk_blocks) bc = chunk_blocks;
            int e_off = bstart * 256;
            if (nchunk > 1)
                hw_kernel<<<dim3(bc * 8), dim3(256), 0, stream>>>(ef, w1, b1, hwf, e_off);
            msg_kernel<<<dim3(bc), dim3(256), 0, stream>>>(hwf, w2f, h, src, dst, sbuf, e_off);
        }
        gru_kernel<<<dim3((N_NODES + 63) / 64), dim3(256), 0, stream>>>(
            sbuf, cnt, cb, gwih, gwhh, gbih, gbhh, h);
    }

    // ---- Set2Set (pooled write fused into last attn) ----
    for (int st = 0; st < 3; ++st) {
        s2s_lstm_kernel<<<dim3((N_GRAPHS + 7) / 8), dim3(256), 0, stream>>>(
            lwih, lwhh, lbih, lbhh, hs, cs, rnum, denom, st == 0 ? 1 : 0);
        s2s_attn_kernel<<<dim3((N_GRAPHS + 7) / 8), dim3(256), 0, stream>>>(
            h, hs, gstart, rnum, denom, out, st == 2 ? 1 : 0);
    }
}